// Round 5
// baseline (371.230 us; speedup 1.0000x reference)
//
#include <hip/hip_runtime.h>
#include <hip/hip_bf16.h>

#define EPSF 1e-5f

typedef __bf16 bf16x8 __attribute__((ext_vector_type(8)));
typedef float  f32x4  __attribute__((ext_vector_type(4)));
#define MFMA16(a, b, c) __builtin_amdgcn_mfma_f32_16x16x32_bf16((a), (b), (c), 0, 0, 0)

__device__ __forceinline__ bf16x8 ld_bf8(const __bf16* p) { return *(const bf16x8*)p; }

__device__ __forceinline__ unsigned short f2bf(float x) {
    unsigned int u = __float_as_uint(x);
    unsigned int r = (u + 0x7fffu + ((u >> 16) & 1u)) >> 16;
    return (unsigned short)r;
}

// Packed fragment layout: [n>>4][k>>5][(k>>3)&3][n&15][k&7]
// -> per (16-col tile, 32-k slice) one wave B-fragment = 1024 contiguous bytes.
__device__ __forceinline__ size_t pk_idx(int n, int k, int K) {
    return ((size_t)(((n >> 4) * (K >> 5) + (k >> 5)) * 4 + ((k >> 3) & 3)) * 16
            + (n & 15)) * 8 + (k & 7);
}

// ============================================================================
// setup1: gn_partial | stylegp | 4x wtrans | pos | kvproj
// grid = 1024 + 32 + 64 + 64 + 128 + 128 + 256 + 256 = 1952
// Serial-dot roles rewritten as wave-split-k + LDS reduce (latency fix).
// ============================================================================
__device__ void wtrans_body(const float* __restrict__ W, unsigned short* __restrict__ Wt,
                            int K, int N, int L, int t, float* tile /*32x33*/) {
    int ktiles = K >> 5;
    int kt = L % ktiles, ntl = L / ktiles;
    int k0 = kt * 32, n0 = ntl * 32;
    int tc = t & 31, tr = t >> 5;
#pragma unroll
    for (int j = 0; j < 4; j++)
        tile[(tr + j * 8) * 33 + tc] = W[(size_t)(k0 + tr + j * 8) * N + n0 + tc];
    __syncthreads();
#pragma unroll
    for (int j = 0; j < 4; j++) {
        int r = tr + j * 8;
        Wt[pk_idx(n0 + r, k0 + tc, K)] = f2bf(tile[tc * 33 + r]);
    }
}

__global__ __launch_bounds__(256) void setup1_kernel(
    const float* __restrict__ x, float* __restrict__ part,
    const float* __restrict__ style, const float* __restrict__ Wg,
    const float* __restrict__ bg, const float* __restrict__ Ws,
    const float* __restrict__ bs, float* __restrict__ gp,
    const float* __restrict__ Wp1, const float* __restrict__ bp1,
    const float* __restrict__ Wp2, const float* __restrict__ bp2,
    float* __restrict__ pos,
    const float* __restrict__ Wq, const float* __restrict__ Wo,
    const float* __restrict__ Wf1, const float* __restrict__ Wf2,
    unsigned short* __restrict__ wq_t, unsigned short* __restrict__ wo_t,
    unsigned short* __restrict__ wf1_t, unsigned short* __restrict__ wf2_t,
    const float* __restrict__ tokens,
    const float* __restrict__ ltg, const float* __restrict__ ltb,
    const float* __restrict__ Wk, const float* __restrict__ bk,
    const float* __restrict__ Wv, const float* __restrict__ bv,
    unsigned short* __restrict__ kb16, unsigned short* __restrict__ vt16)
{
    __shared__ float sm[5248];   // 21 KB, carved per role
    const int L = blockIdx.x, t = threadIdx.x;

    if (L < 1024) {
        // ---- GroupNorm partial stats: (b,g) = L>>4, sub = L&15 --------------
        int bg_ = L >> 4, sub = L & 15;
        const float4* p = (const float4*)(x + bg_ * 262144 + sub * 16384);
        float s = 0.f, q = 0.f;
#pragma unroll
        for (int i = 0; i < 16; i++) {
            float4 v = p[i * 256 + t];
            s += v.x + v.y + v.z + v.w;
            q += v.x * v.x + v.y * v.y + v.z * v.z + v.w * v.w;
        }
#pragma unroll
        for (int off = 32; off; off >>= 1) { s += __shfl_down(s, off); q += __shfl_down(q, off); }
        int lane = t & 63, w = t >> 6;
        if (lane == 0) { sm[w * 2] = s; sm[w * 2 + 1] = q; }
        __syncthreads();
        if (t == 0) {
            part[L * 2]     = sm[0] + sm[2] + sm[4] + sm[6];
            part[L * 2 + 1] = sm[1] + sm[3] + sm[5] + sm[7];
        }
    } else if (L < 1056) {
        // ---- style proj gp: wave-split-k (4 waves x 128 k) + LDS reduce ------
        int lb = L - 1024, b = lb >> 1, role = lb & 1;
        float* st = sm;            // 512
        float* pr = sm + 512;      // 4 x 256
        st[t] = style[b * 512 + t];
        st[256 + t] = style[b * 512 + 256 + t];
        __syncthreads();
        {
            int kc = t >> 6, ln = t & 63;
            float a0 = 0.f, a1 = 0.f, a2 = 0.f, a3 = 0.f;
            for (int i = kc * 128; i < kc * 128 + 128; i++) {
                float sv = st[i];
                const float* wr = &Wg[(size_t)i * 512 + role * 256];
                a0 += sv * wr[ln];       a1 += sv * wr[64 + ln];
                a2 += sv * wr[128 + ln]; a3 += sv * wr[192 + ln];
            }
            pr[kc * 256 + ln]       = a0; pr[kc * 256 + 64 + ln]  = a1;
            pr[kc * 256 + 128 + ln] = a2; pr[kc * 256 + 192 + ln] = a3;
        }
        __syncthreads();
        int c = role * 256 + t;
        float acc = pr[t] + pr[256 + t] + pr[512 + t] + pr[768 + t];
        gp[b * 512 + c] = acc + bg[c];
    } else if (L < 1120) {
        wtrans_body(Wq, wq_t, 256, 256, L - 1056, t, sm);
    } else if (L < 1184) {
        wtrans_body(Wo, wo_t, 256, 256, L - 1120, t, sm);
    } else if (L < 1312) {
        wtrans_body(Wf1, wf1_t, 256, 512, L - 1184, t, sm);
    } else if (L < 1440) {
        wtrans_body(Wf2, wf2_t, 512, 256, L - 1312, t, sm);
    } else if (L < 1696) {
        // ---- pos: 16 positions per block ------------------------------------
        int r = L - 1440, s0 = r * 16;
        float* pe = sm;    // 16 x 256
#pragma unroll
        for (int i = 0; i < 16; i++) {
            int sx = s0 + i;
            float gx = -1.f + 2.f * (float)(sx & 63) * (1.f / 63.f);
            float gy = -1.f + 2.f * (float)(sx >> 6) * (1.f / 63.f);
            float h = gx * Wp1[t] + gy * Wp1[256 + t] + bp1[t];
            pe[i * 256 + t] = h / (1.f + __expf(-h));
        }
        __syncthreads();
        float acc[16];
#pragma unroll
        for (int i = 0; i < 16; i++) acc[i] = 0.f;
#pragma unroll 4
        for (int k = 0; k < 256; k++) {
            float wv = Wp2[k * 256 + t];
#pragma unroll
            for (int i = 0; i < 16; i++) acc[i] += pe[i * 256 + k] * wv;
        }
        float bp = bp2[t];
#pragma unroll
        for (int i = 0; i < 16; i++) pos[(size_t)(s0 + i) * 256 + t] = acc[i] + bp;
    } else {
        // ---- kvproj: split-k styleproj + token-LN + split-k K/V proj ---------
        int lb = L - 1696;
        int b = lb >> 4, tk0 = (lb & 15) * 4;
        float* tr   = sm;            // 1024
        float* st   = sm + 1024;     // 512
        float* prA  = sm + 1536;     // 1024
        float* prKV = sm + 1024;     // 4096 (overlays st/prA in phase C)
        float* red  = sm + 5120;     // 32
        st[t] = style[b * 512 + t];
        st[256 + t] = style[b * 512 + 256 + t];
        __syncthreads();
        const int wv_ = t >> 6, ln = t & 63;
        // phase A: ts = style @ Ws (wave-split-k)
        {
            float a0 = 0.f, a1 = 0.f, a2 = 0.f, a3 = 0.f;
            for (int i = wv_ * 128; i < wv_ * 128 + 128; i++) {
                float sv = st[i];
                const float* wr = &Ws[(size_t)i * 256];
                a0 += sv * wr[ln];       a1 += sv * wr[64 + ln];
                a2 += sv * wr[128 + ln]; a3 += sv * wr[192 + ln];
            }
            prA[wv_ * 256 + ln]       = a0; prA[wv_ * 256 + 64 + ln]  = a1;
            prA[wv_ * 256 + 128 + ln] = a2; prA[wv_ * 256 + 192 + ln] = a3;
        }
        __syncthreads();
        const float ts = prA[t] + prA[256 + t] + prA[512 + t] + prA[768 + t] + bs[t];
        // phase B: token LN
        const float gv = ltg[t], btv = ltb[t];
#pragma unroll
        for (int j = 0; j < 4; j++) {
            float val = tokens[(tk0 + j) * 256 + t] + ts;
            tr[j * 256 + t] = val;
            float s = val, q = val * val;
#pragma unroll
            for (int off = 32; off; off >>= 1) { s += __shfl_down(s, off); q += __shfl_down(q, off); }
            if (ln == 0) { red[j * 8 + wv_ * 2] = s; red[j * 8 + wv_ * 2 + 1] = q; }
        }
        __syncthreads();
#pragma unroll
        for (int j = 0; j < 4; j++) {
            float s = red[j * 8] + red[j * 8 + 2] + red[j * 8 + 4] + red[j * 8 + 6];
            float q = red[j * 8 + 1] + red[j * 8 + 3] + red[j * 8 + 5] + red[j * 8 + 7];
            float m = s * (1.f / 256.f);
            float var = q * (1.f / 256.f) - m * m;
            float r = rsqrtf(var + EPSF);
            tr[j * 256 + t] = (tr[j * 256 + t] - m) * r * gv + btv;
        }
        __syncthreads();
        // phase C: K (waves 0,1) / V (waves 2,3), each pair split-k by 128
        {
            const int isV = wv_ >> 1, kc2 = wv_ & 1;
            const float* Wm = isV ? Wv : Wk;
            float acc[4][4];
#pragma unroll
            for (int cg = 0; cg < 4; cg++)
#pragma unroll
                for (int j = 0; j < 4; j++) acc[cg][j] = 0.f;
            for (int i = kc2 * 128; i < kc2 * 128 + 128; i++) {
                const float* wr = &Wm[(size_t)i * 256];
                float w0 = wr[ln], w1 = wr[64 + ln], w2 = wr[128 + ln], w3 = wr[192 + ln];
                float t0 = tr[i], t1 = tr[256 + i], t2 = tr[512 + i], t3 = tr[768 + i];
                acc[0][0] += w0 * t0; acc[0][1] += w0 * t1; acc[0][2] += w0 * t2; acc[0][3] += w0 * t3;
                acc[1][0] += w1 * t0; acc[1][1] += w1 * t1; acc[1][2] += w1 * t2; acc[1][3] += w1 * t3;
                acc[2][0] += w2 * t0; acc[2][1] += w2 * t1; acc[2][2] += w2 * t2; acc[2][3] += w2 * t3;
                acc[3][0] += w3 * t0; acc[3][1] += w3 * t1; acc[3][2] += w3 * t2; acc[3][3] += w3 * t3;
            }
#pragma unroll
            for (int cg = 0; cg < 4; cg++)
#pragma unroll
                for (int j = 0; j < 4; j++)
                    prKV[((isV * 2 + kc2) * 4 + j) * 256 + cg * 64 + ln] = acc[cg][j];
        }
        __syncthreads();
        float ak[4], av4[4];
#pragma unroll
        for (int j = 0; j < 4; j++) {
            ak[j]  = prKV[j * 256 + t]        + prKV[(4 + j) * 256 + t];
            av4[j] = prKV[(8 + j) * 256 + t]  + prKV[(12 + j) * 256 + t];
        }
        float bkv = bk[t], bvv = bv[t];
        // K packed: frag(h, nt, k0) lane l16 = token, elems = head channels
        {
            int h = t >> 6, k0c = (t >> 5) & 1, qd = (t >> 3) & 3, e = t & 7;
#pragma unroll
            for (int j = 0; j < 4; j++) {
                int tok = tk0 + j;
                kb16[(size_t)b * 16384
                     + ((((h * 4 + (tok >> 4)) * 2 + k0c) * 4 + qd) * 16 + (tok & 15)) * 8 + e]
                    = f2bf(ak[j] + bkv);
            }
        }
        // V packed: frag(h, nt, k0) lane l16 = ch, elems = tokens
        {
            int h = t >> 6, ntv = (t >> 4) & 3, l16v = t & 15;
            int k0t = tk0 >> 5, qdt = (tk0 >> 3) & 3, et0 = tk0 & 7;
            ushort4 vp;
            vp.x = f2bf(av4[0] + bvv); vp.y = f2bf(av4[1] + bvv);
            vp.z = f2bf(av4[2] + bvv); vp.w = f2bf(av4[3] + bvv);
            *(ushort4*)&vt16[(size_t)b * 16384
                + ((((h * 4 + ntv) * 2 + k0t) * 4 + qdt) * 16 + l16v) * 8 + et0] = vp;
        }
    }
}

// ============================================================================
// Mega kernel v6. Block = (b, 32-row s-tile). LDS = 35,328 B -> 4 blocks/CU.
// Register peaks cut below 128: S4 = 2-pass K-split; FF1 = 2-pass row-split.
// ============================================================================
__global__ __launch_bounds__(256, 4) void mega_kernel(
    const float* __restrict__ x, const float* __restrict__ part,
    const float* __restrict__ pos,
    const __bf16* __restrict__ kb, const __bf16* __restrict__ vt,
    const float* __restrict__ gp,
    const float* __restrict__ lnq_g, const float* __restrict__ lnq_b,
    const float* __restrict__ lnf_g, const float* __restrict__ lnf_b,
    const __bf16* __restrict__ Wq_t, const float* __restrict__ bq,
    const __bf16* __restrict__ Wo_t, const float* __restrict__ bo,
    const __bf16* __restrict__ Wf1_t, const float* __restrict__ bf1,
    const __bf16* __restrict__ Wf2_t, const float* __restrict__ bf2,
    const float* __restrict__ gamma, float* __restrict__ out)
{
    __shared__ __align__(16) unsigned char smraw[35328];
    __bf16* Ab  = (__bf16*)smraw;                 // 32 x 264 bf16 = 16,896 B
    __bf16* PsB = (__bf16*)(smraw + 16896);       // 18,432 B scratch region
    __bf16* H   = (__bf16*)smraw;                 // overlay: 32 x 536 bf16 = 34,304 B
    float*  T   = (float*)smraw;                  // overlay: 32 x 268 f32  = 34,304 B
    float* psum   = (float*)(smraw + 16896);      // stats overlays (PsB region)
    float* psq    = psum + 256;
    float* rowred = psum + 512;

    const int blk  = blockIdx.x;        // 2048 = 16 b * 128 tiles
    const int b    = blk >> 7;
    const int s0   = (blk & 127) * 32;
    const int t    = threadIdx.x;
    const int w    = t >> 6;
    const int lane = t & 63;
    const int quad = lane >> 4;
    const int l16  = lane & 15;

    // int fragment offsets (SGPR base + 32-bit voffset addressing)
    const int woff   = quad * 128 + l16 * 8;
    const int qkbase = w * 16384 + woff;              // Wq_t / Wo_t: +(nt*8+ks)*512
    const int ffbase = w * 32768 + woff;              // Wf1_t: +(c*8+ks)*512 ; Wf2_t: +(nt*16+k0)*512
    const int kvbase = b * 16384 + w * 4096 + woff;   // kb / vt: +(nt*2+k0)*512

    const f32x4 z4 = {0.f, 0.f, 0.f, 0.f};

    // ---- prologue: GN stats from part ----------------------------------------
    if (t < 64) {
        int g = t >> 4, sub = t & 15;
        float s = part[((b * 4 + g) * 16 + sub) * 2];
        float q = part[((b * 4 + g) * 16 + sub) * 2 + 1];
#pragma unroll
        for (int off = 8; off; off >>= 1) { s += __shfl_xor(s, off); q += __shfl_xor(q, off); }
        if (sub == 0) {
            float m   = s * (1.f / 262144.f);
            float var = q * (1.f / 262144.f) - m * m;
            psum[g]     = m;
            psum[4 + g] = rsqrtf(var + EPSF);
        }
    }
    __syncthreads();
    const float mg = psum[t >> 6];
    const float rg = psum[4 + (t >> 6)];

    // ---- S1: Ab = bf16(GN(x)+pos); row stats; LN_q in place ------------------
    {
        const float4* xp = (const float4*)(x + (size_t)(b * 256 + t) * 4096 + s0);
        float xv[32];
#pragma unroll
        for (int i = 0; i < 8; i++) {
            float4 v = xp[i];
            xv[4*i] = v.x; xv[4*i+1] = v.y; xv[4*i+2] = v.z; xv[4*i+3] = v.w;
        }
#pragma unroll
        for (int i = 0; i < 32; i++)
            Ab[i * 264 + t] = (__bf16)((xv[i] - mg) * rg + pos[(size_t)(s0 + i) * 256 + t]);
    }
    __syncthreads();
    {
        int sl = t & 31, cg = t >> 5;
        float s = 0.f, q = 0.f;
#pragma unroll
        for (int j = 0; j < 4; j++) {
            bf16x8 v8 = ld_bf8(&Ab[sl * 264 + cg * 32 + j * 8]);
#pragma unroll
            for (int e = 0; e < 8; e++) { float f = (float)v8[e]; s += f; q += f * f; }
        }
        psum[cg * 32 + sl] = s; psq[cg * 32 + sl] = q;
    }
    __syncthreads();
    if (t < 32) {
        float S = 0.f, Q = 0.f;
        for (int p = 0; p < 8; p++) { S += psum[p * 32 + t]; Q += psq[p * 32 + t]; }
        float m = S * (1.f / 256.f);
        float var = Q * (1.f / 256.f) - m * m;
        rowred[t * 2] = m; rowred[t * 2 + 1] = rsqrtf(var + EPSF);
    }
    __syncthreads();
    {
        float gq = lnq_g[t], bqv = lnq_b[t];
#pragma unroll
        for (int i = 0; i < 32; i++) {
            float v = (float)Ab[i * 264 + t];
            Ab[i * 264 + t] = (__bf16)((v - rowred[i * 2]) * rowred[i * 2 + 1] * gq + bqv);
        }
    }
    __syncthreads();

    // ---- S2: q = Ab @ Wq + bq -> Ab (wave: 32 rows x 64 cols) ----------------
    {
        bf16x8 af[2][8];
#pragma unroll
        for (int rt = 0; rt < 2; rt++)
#pragma unroll
            for (int ks = 0; ks < 8; ks++)
                af[rt][ks] = ld_bf8(&Ab[(rt * 16 + l16) * 264 + ks * 32 + quad * 8]);
        __syncthreads();   // all waves' A-frags loaded before Ab overwrite
#pragma unroll
        for (int nt = 0; nt < 4; nt++) {
            int n = w * 64 + nt * 16 + l16;
            f32x4 a0 = z4, a1 = z4;
#pragma unroll
            for (int ks = 0; ks < 8; ks++) {
                bf16x8 bv = ld_bf8(&Wq_t[qkbase + (nt * 8 + ks) * 512]);
                a0 = MFMA16(af[0][ks], bv, a0);
                a1 = MFMA16(af[1][ks], bv, a1);
            }
            float bias = bq[n];
#pragma unroll
            for (int r = 0; r < 4; r++) {
                Ab[(quad * 4 + r) * 264 + n]        = (__bf16)(a0[r] + bias);
                Ab[(16 + quad * 4 + r) * 264 + n]   = (__bf16)(a1[r] + bias);
            }
        }
    }
    // no barrier: S3 wave w reads exactly the cols wave w just wrote

    // ---- S3: attention, head = w, 32 rows ------------------------------------
    {
        const int h = w;
        __bf16* Psw = PsB + w * 32 * 72;
        bf16x8 qa[2][2];
#pragma unroll
        for (int rt = 0; rt < 2; rt++)
#pragma unroll
            for (int k0 = 0; k0 < 2; k0++)
                qa[rt][k0] = ld_bf8(&Ab[(rt * 16 + l16) * 264 + h * 64 + k0 * 32 + quad * 8]);
        f32x4 sa[2][4];
#pragma unroll
        for (int rt = 0; rt < 2; rt++)
#pragma unroll
            for (int nt = 0; nt < 4; nt++) sa[rt][nt] = z4;
#pragma unroll
        for (int nt = 0; nt < 4; nt++)
#pragma unroll
            for (int k0 = 0; k0 < 2; k0++) {
                bf16x8 kv8 = ld_bf8(&kb[kvbase + (nt * 2 + k0) * 512]);
                sa[0][nt] = MFMA16(qa[0][k0], kv8, sa[0][nt]);
                sa[1][nt] = MFMA16(qa[1][k0], kv8, sa[1][nt]);
            }
        // softmax per row; P -> Psw (bf16)
#pragma unroll
        for (int rt = 0; rt < 2; rt++)
#pragma unroll
            for (int r = 0; r < 4; r++) {
                float e0 = sa[rt][0][r] * 0.25f, e1 = sa[rt][1][r] * 0.25f;
                float e2 = sa[rt][2][r] * 0.25f, e3 = sa[rt][3][r] * 0.25f;
                float mx = fmaxf(fmaxf(e0, e1), fmaxf(e2, e3));
#pragma unroll
                for (int off = 1; off < 16; off <<= 1) mx = fmaxf(mx, __shfl_xor(mx, off));
                e0 = __expf(e0 - mx); e1 = __expf(e1 - mx);
                e2 = __expf(e2 - mx); e3 = __expf(e3 - mx);
                float sum = e0 + e1 + e2 + e3;
#pragma unroll
                for (int off = 1; off < 16; off <<= 1) sum += __shfl_xor(sum, off);
                float inv = 1.f / sum;
                int row = rt * 16 + quad * 4 + r;
                Psw[row * 72 +  0 + l16] = (__bf16)(e0 * inv);
                Psw[row * 72 + 16 + l16] = (__bf16)(e1 * inv);
                Psw[row * 72 + 32 + l16] = (__bf16)(e2 * inv);
                Psw[row * 72 + 48 + l16] = (__bf16)(e3 * inv);
            }
        // O = P @ V_h -> Ab cols [h*64, h*64+64)
        bf16x8 pa[2][2];
#pragma unroll
        for (int rt = 0; rt < 2; rt++)
#pragma unroll
            for (int k0 = 0; k0 < 2; k0++)
                pa[rt][k0] = ld_bf8(&Psw[(rt * 16 + l16) * 72 + k0 * 32 + quad * 8]);
#pragma unroll
        for (int nt = 0; nt < 4; nt++) {
            f32x4 o0 = z4, o1 = z4;
#pragma unroll
            for (int k0 = 0; k0 < 2; k0++) {
                bf16x8 vv = ld_bf8(&vt[kvbase + (nt * 2 + k0) * 512]);
                o0 = MFMA16(pa[0][k0], vv, o0);
                o1 = MFMA16(pa[1][k0], vv, o1);
            }
#pragma unroll
            for (int r = 0; r < 4; r++) {
                Ab[(quad * 4 + r) * 264 + h * 64 + nt * 16 + l16]      = (__bf16)o0[r];
                Ab[(16 + quad * 4 + r) * 264 + h * 64 + nt * 16 + l16] = (__bf16)o1[r];
            }
        }
    }
    __syncthreads();

    // ---- S4: sc = Ab @ Wo + bo -> scf regs (2-pass K-split, bias in init) ----
    f32x4 scf[2][4];
    {
#pragma unroll
        for (int nt = 0; nt < 4; nt++) {
            float bias = bo[w * 64 + nt * 16 + l16];
            f32x4 bi = {bias, bias, bias, bias};
            scf[0][nt] = bi;
            scf[1][nt] = bi;
        }
#pragma unroll
        for (int kh = 0; kh < 2; kh++) {
            bf16x8 af[2][4];
#pragma unroll
            for (int rt = 0; rt < 2; rt++)
#pragma unroll
                for (int kk = 0; kk < 4; kk++)
                    af[rt][kk] = ld_bf8(&Ab[(rt * 16 + l16) * 264 + (kh * 4 + kk) * 32 + quad * 8]);
#pragma unroll
            for (int nt = 0; nt < 4; nt++) {
#pragma unroll
                for (int kk = 0; kk < 4; kk++) {
                    bf16x8 bv = ld_bf8(&Wo_t[qkbase + (nt * 8 + kh * 4 + kk) * 512]);
                    scf[0][nt] = MFMA16(af[0][kk], bv, scf[0][nt]);
                    scf[1][nt] = MFMA16(af[1][kk], bv, scf[1][nt]);
                }
            }
        }
    }

    // ---- S5: row stats of sc from registers ----------------------------------
    {
#pragma unroll
        for (int rt = 0; rt < 2; rt++)
#pragma unroll
            for (int r = 0; r < 4; r++) {
                float s = scf[rt][0][r] + scf[rt][1][r] + scf[rt][2][r] + scf[rt][3][r];
                float q = scf[rt][0][r] * scf[rt][0][r] + scf[rt][1][r] * scf[rt][1][r]
                        + scf[rt][2][r] * scf[rt][2][r] + scf[rt][3][r] * scf[rt][3][r];
#pragma unroll
                for (int mk = 1; mk < 16; mk <<= 1) { s += __shfl_xor(s, mk); q += __shfl_xor(q, mk); }
                if (l16 == 0) {
                    int row = rt * 16 + quad * 4 + r;
                    psum[row * 4 + w] = s;
                    psq[row * 4 + w]  = q;
                }
            }
    }
    __syncthreads();
    if (t < 32) {
        float S = psum[t * 4] + psum[t * 4 + 1] + psum[t * 4 + 2] + psum[t * 4 + 3];
        float Q = psq[t * 4]  + psq[t * 4 + 1]  + psq[t * 4 + 2]  + psq[t * 4 + 3];
        float m = S * (1.f / 256.f);
        float var = Q * (1.f / 256.f) - m * m;
        rowred[t * 2] = m; rowred[t * 2 + 1] = rsqrtf(var + EPSF);
    }
    __syncthreads();

    // ---- LN_f from registers -> Ab; fold scf+bf2 into acc2 (kills scf) -------
    f32x4 acc2[2][4];
    {
        float gf[4], bff[4];
#pragma unroll
        for (int nt = 0; nt < 4; nt++) {
            int n = w * 64 + nt * 16 + l16;
            gf[nt] = lnf_g[n]; bff[nt] = lnf_b[n];
        }
#pragma unroll
        for (int rt = 0; rt < 2; rt++)
#pragma unroll
            for (int r = 0; r < 4; r++) {
                int row = rt * 16 + quad * 4 + r;
                float m = rowred[row * 2], ri = rowred[row * 2 + 1];
#pragma unroll
                for (int nt = 0; nt < 4; nt++) {
                    int n = w * 64 + nt * 16 + l16;
                    Ab[row * 264 + n] = (__bf16)((scf[rt][nt][r] - m) * ri * gf[nt] + bff[nt]);
                }
            }
#pragma unroll
        for (int nt = 0; nt < 4; nt++) {
            float b2 = bf2[w * 64 + nt * 16 + l16];
#pragma unroll
            for (int rt = 0; rt < 2; rt++) {
                acc2[rt][nt] = scf[rt][nt];
#pragma unroll
                for (int r = 0; r < 4; r++) acc2[rt][nt][r] += b2;
            }
        }
    }
    __syncthreads();

    // ---- FF1: 2-pass row-split into H overlay --------------------------------
    {
        // pass 1: rows 16..31. H rows 16-31 live at bytes >= 17,152 -> never
        // clobber Ab (ends 16,896); no barrier needed inside this pass.
        {
            bf16x8 fa1[8];
#pragma unroll
            for (int ks = 0; ks < 8; ks++)
                fa1[ks] = ld_bf8(&Ab[(16 + l16) * 264 + ks * 32 + quad * 8]);
#pragma unroll
            for (int c = 0; c < 8; c++) {
                int n1 = w * 128 + c * 16 + l16;
                f32x4 h1 = z4;
#pragma unroll
                for (int ks = 0; ks < 8; ks++) {
                    bf16x8 bv = ld_bf8(&Wf1_t[ffbase + (c * 8 + ks) * 512]);
                    h1 = MFMA16(fa1[ks], bv, h1);
                }
                float b1v = bf1[n1];
#pragma unroll
                for (int r = 0; r < 4; r++) {
                    float u1 = h1[r] + b1v;
                    H[(16 + quad * 4 + r) * 536 + n1] = (__bf16)(u1 / (1.f + __expf(-u1)));
                }
            }
        }
        // pass 2: rows 0..15. Barrier after fa0 loads: every wave has finished
        // ALL Ab reads (pass1 + these) before any H row 0-15 write clobbers Ab.
        {
            bf16x8 fa0[8];
#pragma unroll
            for (int ks = 0; ks < 8; ks++)
                fa0[ks] = ld_bf8(&Ab[l16 * 264 + ks * 32 + quad * 8]);
            __syncthreads();
#pragma unroll
            for (int c = 0; c < 8; c++) {
                int n1 = w * 128 + c * 16 + l16;
                f32x4 h0 = z4;
#pragma unroll
                for (int ks = 0; ks < 8; ks++) {
                    bf16x8 bv = ld_bf8(&Wf1_t[ffbase + (c * 8 + ks) * 512]);
                    h0 = MFMA16(fa0[ks], bv, h0);
                }
                float b1v = bf1[n1];
#pragma unroll
                for (int r = 0; r < 4; r++) {
                    float u0 = h0[r] + b1v;
                    H[(quad * 4 + r) * 536 + n1] = (__bf16)(u0 / (1.f + __expf(-u0)));
                }
            }
        }
        __syncthreads();   // full H visible
        // FF2: accumulate over K=512
#pragma unroll
        for (int k0 = 0; k0 < 16; k0++) {
            bf16x8 ha0 = ld_bf8(&H[(size_t)l16 * 536 + k0 * 32 + quad * 8]);
            bf16x8 ha1 = ld_bf8(&H[(size_t)(16 + l16) * 536 + k0 * 32 + quad * 8]);
#pragma unroll
            for (int nt = 0; nt < 4; nt++) {
                bf16x8 bv = ld_bf8(&Wf2_t[ffbase + (nt * 16 + k0) * 512]);
                acc2[0][nt] = MFMA16(ha0, bv, acc2[0][nt]);
                acc2[1][nt] = MFMA16(ha1, bv, acc2[1][nt]);
            }
        }
    }
    __syncthreads();   // all H reads done before T overlay writes

    // ---- sc_final (= acc2, includes sc + bf2) -> T (f32 transpose) -----------
    {
#pragma unroll
        for (int nt = 0; nt < 4; nt++) {
            int n = w * 64 + nt * 16 + l16;
#pragma unroll
            for (int rt = 0; rt < 2; rt++)
#pragma unroll
                for (int r = 0; r < 4; r++)
                    T[(rt * 16 + quad * 4 + r) * 268 + n] = acc2[rt][nt][r];
        }
    }
    __syncthreads();

    // ---- S6: out[b,c,s] = GN(x)*scale + shift + sc*gamma ---------------------
    {
        const float scl = gp[b * 512 + t];
        const float sft = gp[b * 512 + 256 + t];
        const float gm  = gamma[t];
        const float4* xp = (const float4*)(x + (size_t)(b * 256 + t) * 4096 + s0);
        float4* op = (float4*)(out + (size_t)(b * 256 + t) * 4096 + s0);
#pragma unroll
        for (int ii = 0; ii < 8; ii++) {
            float4 xv = xp[ii];
            float4 o;
            o.x = (xv.x - mg) * rg * scl + sft + T[(ii * 4 + 0) * 268 + t] * gm;
            o.y = (xv.y - mg) * rg * scl + sft + T[(ii * 4 + 1) * 268 + t] * gm;
            o.z = (xv.z - mg) * rg * scl + sft + T[(ii * 4 + 2) * 268 + t] * gm;
            o.w = (xv.w - mg) * rg * scl + sft + T[(ii * 4 + 3) * 268 + t] * gm;
            op[ii] = o;
        }
    }
}

// ============================================================================
extern "C" void kernel_launch(void* const* d_in, const int* in_sizes, int n_in,
                              void* d_out, int out_size, void* d_ws, size_t ws_size,
                              hipStream_t stream) {
    (void)in_sizes; (void)n_in; (void)out_size; (void)ws_size;
    const float* x      = (const float*)d_in[0];
    const float* style  = (const float*)d_in[1];
    const float* Wg     = (const float*)d_in[2];
    const float* bg     = (const float*)d_in[3];
    const float* tokens = (const float*)d_in[4];
    const float* Ws     = (const float*)d_in[5];
    const float* bs     = (const float*)d_in[6];
    const float* Wp1    = (const float*)d_in[7];
    const float* bp1    = (const float*)d_in[8];
    const float* Wp2    = (const float*)d_in[9];
    const float* bp2    = (const float*)d_in[10];
    const float* ln_t_g = (const float*)d_in[11];
    const float* ln_t_b = (const float*)d_in[12];
    const float* ln_q_g = (const float*)d_in[13];
    const float* ln_q_b = (const float*)d_in[14];
    const float* ln_f_g = (const float*)d_in[15];
    const float* ln_f_b = (const float*)d_in[16];
    const float* Wq     = (const float*)d_in[17];
    const float* bq     = (const float*)d_in[18];
    const float* Wk     = (const float*)d_in[19];
    const float* bk     = (const float*)d_in[20];
    const float* Wv     = (const float*)d_in[21];
    const float* bv     = (const float*)d_in[22];
    const float* Wo     = (const float*)d_in[23];
    const float* bo     = (const float*)d_in[24];
    const float* Wf1    = (const float*)d_in[25];
    const float* bf1    = (const float*)d_in[26];
    const float* Wf2    = (const float*)d_in[27];
    const float* bf2    = (const float*)d_in[28];
    const float* gamma  = (const float*)d_in[29];
    float* out = (float*)d_out;

    // d_ws layout (~7.1 MB)
    float* ws = (float*)d_ws;
    float* part  = ws;               // 2048
    float* stats = part  + 2048;     // 128  (unused, kept for layout stability)
    float* gpb   = stats + 128;      // 8192
    float* tmp_s = gpb   + 8192;     // 4096 (unused)
    float* tokb  = tmp_s + 4096;     // 262144 (unused)
    float* posb  = tokb  + 262144;   // 1048576
    unsigned short* kb16  = (unsigned short*)(posb + 1048576); // 262144 bf16
    unsigned short* vt16  = kb16  + 262144;                    // 262144
    unsigned short* wq_t  = vt16  + 262144;                    // 65536
    unsigned short* wo_t  = wq_t  + 65536;                     // 65536
    unsigned short* wf1_t = wo_t  + 65536;                     // 131072
    unsigned short* wf2_t = wf1_t + 131072;                    // 131072

    setup1_kernel<<<1952, 256, 0, stream>>>(x, part, style, Wg, bg, Ws, bs, gpb,
                                            Wp1, bp1, Wp2, bp2, posb,
                                            Wq, Wo, Wf1, Wf2,
                                            wq_t, wo_t, wf1_t, wf2_t,
                                            tokens, ln_t_g, ln_t_b,
                                            Wk, bk, Wv, bv, kb16, vt16);
    mega_kernel<<<2048, 256, 0, stream>>>(x, part, posb,
                                          (const __bf16*)kb16, (const __bf16*)vt16, gpb,
                                          ln_q_g, ln_q_b, ln_f_g, ln_f_b,
                                          (const __bf16*)wq_t, bq,
                                          (const __bf16*)wo_t, bo,
                                          (const __bf16*)wf1_t, bf1,
                                          (const __bf16*)wf2_t, bf2,
                                          gamma, out);
}

// Round 6
// 365.810 us; speedup vs baseline: 1.0148x; 1.0148x over previous
//
#include <hip/hip_runtime.h>
#include <hip/hip_bf16.h>

#define EPSF 1e-5f

typedef __bf16 bf16x8 __attribute__((ext_vector_type(8)));
typedef float  f32x4  __attribute__((ext_vector_type(4)));
#define MFMA16(a, b, c) __builtin_amdgcn_mfma_f32_16x16x32_bf16((a), (b), (c), 0, 0, 0)

__device__ __forceinline__ bf16x8 ld_bf8(const __bf16* p) { return *(const bf16x8*)p; }

__device__ __forceinline__ unsigned short f2bf(float x) {
    unsigned int u = __float_as_uint(x);
    unsigned int r = (u + 0x7fffu + ((u >> 16) & 1u)) >> 16;
    return (unsigned short)r;
}

// Packed fragment layout: [n>>4][k>>5][(k>>3)&3][n&15][k&7]
// -> per (16-col tile, 32-k slice) one wave B-fragment = 1024 contiguous bytes.
__device__ __forceinline__ size_t pk_idx(int n, int k, int K) {
    return ((size_t)(((n >> 4) * (K >> 5) + (k >> 5)) * 4 + ((k >> 3) & 3)) * 16
            + (n & 15)) * 8 + (k & 7);
}

// ============================================================================
// setup1: HEAVY-FIRST role order: kvproj | stylegp | pos | 4x wtrans | gn
// grid = 256 + 32 + 256 + 64 + 64 + 128 + 128 + 1024 = 1952
// Heavy blocks at low blockIdx start immediately; gn flood fills the rest.
// ============================================================================
__device__ void wtrans_body(const float* __restrict__ W, unsigned short* __restrict__ Wt,
                            int K, int N, int L, int t, float* tile /*32x33*/) {
    int ktiles = K >> 5;
    int kt = L % ktiles, ntl = L / ktiles;
    int k0 = kt * 32, n0 = ntl * 32;
    int tc = t & 31, tr = t >> 5;
#pragma unroll
    for (int j = 0; j < 4; j++)
        tile[(tr + j * 8) * 33 + tc] = W[(size_t)(k0 + tr + j * 8) * N + n0 + tc];
    __syncthreads();
#pragma unroll
    for (int j = 0; j < 4; j++) {
        int r = tr + j * 8;
        Wt[pk_idx(n0 + r, k0 + tc, K)] = f2bf(tile[tc * 33 + r]);
    }
}

__global__ __launch_bounds__(256) void setup1_kernel(
    const float* __restrict__ x, float* __restrict__ part,
    const float* __restrict__ style, const float* __restrict__ Wg,
    const float* __restrict__ bg, const float* __restrict__ Ws,
    const float* __restrict__ bs, float* __restrict__ gp,
    const float* __restrict__ Wp1, const float* __restrict__ bp1,
    const float* __restrict__ Wp2, const float* __restrict__ bp2,
    float* __restrict__ pos,
    const float* __restrict__ Wq, const float* __restrict__ Wo,
    const float* __restrict__ Wf1, const float* __restrict__ Wf2,
    unsigned short* __restrict__ wq_t, unsigned short* __restrict__ wo_t,
    unsigned short* __restrict__ wf1_t, unsigned short* __restrict__ wf2_t,
    const float* __restrict__ tokens,
    const float* __restrict__ ltg, const float* __restrict__ ltb,
    const float* __restrict__ Wk, const float* __restrict__ bk,
    const float* __restrict__ Wv, const float* __restrict__ bv,
    unsigned short* __restrict__ kb16, unsigned short* __restrict__ vt16)
{
    __shared__ float sm[5248];   // 21 KB, carved per role
    const int L = blockIdx.x, t = threadIdx.x;

    if (L < 256) {
        // ---- kvproj: split-k styleproj + token-LN + split-k K/V proj ---------
        int b = L >> 4, tk0 = (L & 15) * 4;
        float* tr   = sm;            // 1024
        float* st   = sm + 1024;     // 512
        float* prA  = sm + 1536;     // 1024
        float* prKV = sm + 1024;     // 4096 (overlays st/prA in phase C)
        float* red  = sm + 5120;     // 32
        st[t] = style[b * 512 + t];
        st[256 + t] = style[b * 512 + 256 + t];
        __syncthreads();
        const int wv_ = t >> 6, ln = t & 63;
        // phase A: ts = style @ Ws (wave-split-k, unroll 4 for load overlap)
        {
            float a0 = 0.f, a1 = 0.f, a2 = 0.f, a3 = 0.f;
#pragma unroll 4
            for (int i = wv_ * 128; i < wv_ * 128 + 128; i++) {
                float sv = st[i];
                const float* wr = &Ws[(size_t)i * 256];
                a0 += sv * wr[ln];       a1 += sv * wr[64 + ln];
                a2 += sv * wr[128 + ln]; a3 += sv * wr[192 + ln];
            }
            prA[wv_ * 256 + ln]       = a0; prA[wv_ * 256 + 64 + ln]  = a1;
            prA[wv_ * 256 + 128 + ln] = a2; prA[wv_ * 256 + 192 + ln] = a3;
        }
        __syncthreads();
        const float ts = prA[t] + prA[256 + t] + prA[512 + t] + prA[768 + t] + bs[t];
        // phase B: token LN
        const float gv = ltg[t], btv = ltb[t];
#pragma unroll
        for (int j = 0; j < 4; j++) {
            float val = tokens[(tk0 + j) * 256 + t] + ts;
            tr[j * 256 + t] = val;
            float s = val, q = val * val;
#pragma unroll
            for (int off = 32; off; off >>= 1) { s += __shfl_down(s, off); q += __shfl_down(q, off); }
            if (ln == 0) { red[j * 8 + wv_ * 2] = s; red[j * 8 + wv_ * 2 + 1] = q; }
        }
        __syncthreads();
#pragma unroll
        for (int j = 0; j < 4; j++) {
            float s = red[j * 8] + red[j * 8 + 2] + red[j * 8 + 4] + red[j * 8 + 6];
            float q = red[j * 8 + 1] + red[j * 8 + 3] + red[j * 8 + 5] + red[j * 8 + 7];
            float m = s * (1.f / 256.f);
            float var = q * (1.f / 256.f) - m * m;
            float r = rsqrtf(var + EPSF);
            tr[j * 256 + t] = (tr[j * 256 + t] - m) * r * gv + btv;
        }
        __syncthreads();
        // phase C: K (waves 0,1) / V (waves 2,3), each pair split-k by 128
        {
            const int isV = wv_ >> 1, kc2 = wv_ & 1;
            const float* Wm = isV ? Wv : Wk;
            float acc[4][4];
#pragma unroll
            for (int cg = 0; cg < 4; cg++)
#pragma unroll
                for (int j = 0; j < 4; j++) acc[cg][j] = 0.f;
#pragma unroll 2
            for (int i = kc2 * 128; i < kc2 * 128 + 128; i++) {
                const float* wr = &Wm[(size_t)i * 256];
                float w0 = wr[ln], w1 = wr[64 + ln], w2 = wr[128 + ln], w3 = wr[192 + ln];
                float t0 = tr[i], t1 = tr[256 + i], t2 = tr[512 + i], t3 = tr[768 + i];
                acc[0][0] += w0 * t0; acc[0][1] += w0 * t1; acc[0][2] += w0 * t2; acc[0][3] += w0 * t3;
                acc[1][0] += w1 * t0; acc[1][1] += w1 * t1; acc[1][2] += w1 * t2; acc[1][3] += w1 * t3;
                acc[2][0] += w2 * t0; acc[2][1] += w2 * t1; acc[2][2] += w2 * t2; acc[2][3] += w2 * t3;
                acc[3][0] += w3 * t0; acc[3][1] += w3 * t1; acc[3][2] += w3 * t2; acc[3][3] += w3 * t3;
            }
#pragma unroll
            for (int cg = 0; cg < 4; cg++)
#pragma unroll
                for (int j = 0; j < 4; j++)
                    prKV[((isV * 2 + kc2) * 4 + j) * 256 + cg * 64 + ln] = acc[cg][j];
        }
        __syncthreads();
        float ak[4], av4[4];
#pragma unroll
        for (int j = 0; j < 4; j++) {
            ak[j]  = prKV[j * 256 + t]        + prKV[(4 + j) * 256 + t];
            av4[j] = prKV[(8 + j) * 256 + t]  + prKV[(12 + j) * 256 + t];
        }
        float bkv = bk[t], bvv = bv[t];
        // K packed: frag(h, nt, k0) lane l16 = token, elems = head channels
        {
            int h = t >> 6, k0c = (t >> 5) & 1, qd = (t >> 3) & 3, e = t & 7;
#pragma unroll
            for (int j = 0; j < 4; j++) {
                int tok = tk0 + j;
                kb16[(size_t)b * 16384
                     + ((((h * 4 + (tok >> 4)) * 2 + k0c) * 4 + qd) * 16 + (tok & 15)) * 8 + e]
                    = f2bf(ak[j] + bkv);
            }
        }
        // V packed: frag(h, nt, k0) lane l16 = ch, elems = tokens
        {
            int h = t >> 6, ntv = (t >> 4) & 3, l16v = t & 15;
            int k0t = tk0 >> 5, qdt = (tk0 >> 3) & 3, et0 = tk0 & 7;
            ushort4 vp;
            vp.x = f2bf(av4[0] + bvv); vp.y = f2bf(av4[1] + bvv);
            vp.z = f2bf(av4[2] + bvv); vp.w = f2bf(av4[3] + bvv);
            *(ushort4*)&vt16[(size_t)b * 16384
                + ((((h * 4 + ntv) * 2 + k0t) * 4 + qdt) * 16 + l16v) * 8 + et0] = vp;
        }
    } else if (L < 288) {
        // ---- style proj gp: wave-split-k (4 waves x 128 k) + LDS reduce ------
        int lb = L - 256, b = lb >> 1, role = lb & 1;
        float* st = sm;            // 512
        float* pr = sm + 512;      // 4 x 256
        st[t] = style[b * 512 + t];
        st[256 + t] = style[b * 512 + 256 + t];
        __syncthreads();
        {
            int kc = t >> 6, ln = t & 63;
            float a0 = 0.f, a1 = 0.f, a2 = 0.f, a3 = 0.f;
#pragma unroll 4
            for (int i = kc * 128; i < kc * 128 + 128; i++) {
                float sv = st[i];
                const float* wr = &Wg[(size_t)i * 512 + role * 256];
                a0 += sv * wr[ln];       a1 += sv * wr[64 + ln];
                a2 += sv * wr[128 + ln]; a3 += sv * wr[192 + ln];
            }
            pr[kc * 256 + ln]       = a0; pr[kc * 256 + 64 + ln]  = a1;
            pr[kc * 256 + 128 + ln] = a2; pr[kc * 256 + 192 + ln] = a3;
        }
        __syncthreads();
        int c = role * 256 + t;
        float acc = pr[t] + pr[256 + t] + pr[512 + t] + pr[768 + t];
        gp[b * 512 + c] = acc + bg[c];
    } else if (L < 544) {
        // ---- pos: 16 positions per block ------------------------------------
        int r = L - 288, s0 = r * 16;
        float* pe = sm;    // 16 x 256
#pragma unroll
        for (int i = 0; i < 16; i++) {
            int sx = s0 + i;
            float gx = -1.f + 2.f * (float)(sx & 63) * (1.f / 63.f);
            float gy = -1.f + 2.f * (float)(sx >> 6) * (1.f / 63.f);
            float h = gx * Wp1[t] + gy * Wp1[256 + t] + bp1[t];
            pe[i * 256 + t] = h / (1.f + __expf(-h));
        }
        __syncthreads();
        float acc[16];
#pragma unroll
        for (int i = 0; i < 16; i++) acc[i] = 0.f;
#pragma unroll 4
        for (int k = 0; k < 256; k++) {
            float wv = Wp2[k * 256 + t];
#pragma unroll
            for (int i = 0; i < 16; i++) acc[i] += pe[i * 256 + k] * wv;
        }
        float bp = bp2[t];
#pragma unroll
        for (int i = 0; i < 16; i++) pos[(size_t)(s0 + i) * 256 + t] = acc[i] + bp;
    } else if (L < 608) {
        wtrans_body(Wq, wq_t, 256, 256, L - 544, t, sm);
    } else if (L < 672) {
        wtrans_body(Wo, wo_t, 256, 256, L - 608, t, sm);
    } else if (L < 800) {
        wtrans_body(Wf1, wf1_t, 256, 512, L - 672, t, sm);
    } else if (L < 928) {
        wtrans_body(Wf2, wf2_t, 512, 256, L - 800, t, sm);
    } else {
        // ---- GroupNorm partial stats: (b,g) = lg>>4, sub = lg&15 ------------
        int lg = L - 928;
        int bg_ = lg >> 4, sub = lg & 15;
        const float4* p = (const float4*)(x + bg_ * 262144 + sub * 16384);
        float s = 0.f, q = 0.f;
#pragma unroll
        for (int i = 0; i < 16; i++) {
            float4 v = p[i * 256 + t];
            s += v.x + v.y + v.z + v.w;
            q += v.x * v.x + v.y * v.y + v.z * v.z + v.w * v.w;
        }
#pragma unroll
        for (int off = 32; off; off >>= 1) { s += __shfl_down(s, off); q += __shfl_down(q, off); }
        int lane = t & 63, w = t >> 6;
        if (lane == 0) { sm[w * 2] = s; sm[w * 2 + 1] = q; }
        __syncthreads();
        if (t == 0) {
            part[lg * 2]     = sm[0] + sm[2] + sm[4] + sm[6];
            part[lg * 2 + 1] = sm[1] + sm[3] + sm[5] + sm[7];
        }
    }
}

// ============================================================================
// Mega kernel (exact R4/v5 revert — 178 µs measured). Block = (b, 32-row tile).
// LDS = 35,328 B -> 4 blocks/CU. Packed weights, int offsets, scf fold.
// ============================================================================
__global__ __launch_bounds__(256, 4) void mega_kernel(
    const float* __restrict__ x, const float* __restrict__ part,
    const float* __restrict__ pos,
    const __bf16* __restrict__ kb, const __bf16* __restrict__ vt,
    const float* __restrict__ gp,
    const float* __restrict__ lnq_g, const float* __restrict__ lnq_b,
    const float* __restrict__ lnf_g, const float* __restrict__ lnf_b,
    const __bf16* __restrict__ Wq_t, const float* __restrict__ bq,
    const __bf16* __restrict__ Wo_t, const float* __restrict__ bo,
    const __bf16* __restrict__ Wf1_t, const float* __restrict__ bf1,
    const __bf16* __restrict__ Wf2_t, const float* __restrict__ bf2,
    const float* __restrict__ gamma, float* __restrict__ out)
{
    __shared__ __align__(16) unsigned char smraw[35328];
    __bf16* Ab  = (__bf16*)smraw;                 // 32 x 264 bf16 = 16,896 B
    __bf16* PsB = (__bf16*)(smraw + 16896);       // 18,432 B scratch region
    __bf16* H   = (__bf16*)smraw;                 // overlay: 32 x 536 bf16 = 34,304 B
    float*  T   = (float*)smraw;                  // overlay: 32 x 268 f32  = 34,304 B
    float* psum   = (float*)(smraw + 16896);      // stats overlays (PsB region)
    float* psq    = psum + 256;
    float* rowred = psum + 512;

    const int blk  = blockIdx.x;        // 2048 = 16 b * 128 tiles
    const int b    = blk >> 7;
    const int s0   = (blk & 127) * 32;
    const int t    = threadIdx.x;
    const int w    = t >> 6;
    const int lane = t & 63;
    const int quad = lane >> 4;
    const int l16  = lane & 15;

    // int fragment offsets (SGPR base + 32-bit voffset addressing)
    const int woff   = quad * 128 + l16 * 8;
    const int qkbase = w * 16384 + woff;              // Wq_t / Wo_t: +(nt*8+ks)*512
    const int ffbase = w * 32768 + woff;              // Wf1_t: +(c*8+ks)*512 ; Wf2_t: +(nt*16+k0)*512
    const int kvbase = b * 16384 + w * 4096 + woff;   // kb / vt: +(nt*2+k0)*512

    const f32x4 z4 = {0.f, 0.f, 0.f, 0.f};

    // ---- prologue: GN stats from part ----------------------------------------
    if (t < 64) {
        int g = t >> 4, sub = t & 15;
        float s = part[((b * 4 + g) * 16 + sub) * 2];
        float q = part[((b * 4 + g) * 16 + sub) * 2 + 1];
#pragma unroll
        for (int off = 8; off; off >>= 1) { s += __shfl_xor(s, off); q += __shfl_xor(q, off); }
        if (sub == 0) {
            float m   = s * (1.f / 262144.f);
            float var = q * (1.f / 262144.f) - m * m;
            psum[g]     = m;
            psum[4 + g] = rsqrtf(var + EPSF);
        }
    }
    __syncthreads();
    const float mg = psum[t >> 6];
    const float rg = psum[4 + (t >> 6)];

    // ---- S1: Ab = bf16(GN(x)+pos); row stats; LN_q in place ------------------
    {
        const float4* xp = (const float4*)(x + (size_t)(b * 256 + t) * 4096 + s0);
        float xv[32];
#pragma unroll
        for (int i = 0; i < 8; i++) {
            float4 v = xp[i];
            xv[4*i] = v.x; xv[4*i+1] = v.y; xv[4*i+2] = v.z; xv[4*i+3] = v.w;
        }
#pragma unroll
        for (int i = 0; i < 32; i++)
            Ab[i * 264 + t] = (__bf16)((xv[i] - mg) * rg + pos[(size_t)(s0 + i) * 256 + t]);
    }
    __syncthreads();
    {
        int sl = t & 31, cg = t >> 5;
        float s = 0.f, q = 0.f;
#pragma unroll
        for (int j = 0; j < 4; j++) {
            bf16x8 v8 = ld_bf8(&Ab[sl * 264 + cg * 32 + j * 8]);
#pragma unroll
            for (int e = 0; e < 8; e++) { float f = (float)v8[e]; s += f; q += f * f; }
        }
        psum[cg * 32 + sl] = s; psq[cg * 32 + sl] = q;
    }
    __syncthreads();
    if (t < 32) {
        float S = 0.f, Q = 0.f;
        for (int p = 0; p < 8; p++) { S += psum[p * 32 + t]; Q += psq[p * 32 + t]; }
        float m = S * (1.f / 256.f);
        float var = Q * (1.f / 256.f) - m * m;
        rowred[t * 2] = m; rowred[t * 2 + 1] = rsqrtf(var + EPSF);
    }
    __syncthreads();
    {
        float gq = lnq_g[t], bqv = lnq_b[t];
#pragma unroll
        for (int i = 0; i < 32; i++) {
            float v = (float)Ab[i * 264 + t];
            Ab[i * 264 + t] = (__bf16)((v - rowred[i * 2]) * rowred[i * 2 + 1] * gq + bqv);
        }
    }
    __syncthreads();

    // ---- S2: q = Ab @ Wq + bq -> Ab (wave: 32 rows x 64 cols) ----------------
    {
        bf16x8 af[2][8];
#pragma unroll
        for (int rt = 0; rt < 2; rt++)
#pragma unroll
            for (int ks = 0; ks < 8; ks++)
                af[rt][ks] = ld_bf8(&Ab[(rt * 16 + l16) * 264 + ks * 32 + quad * 8]);
        __syncthreads();   // all waves' A-frags loaded before Ab overwrite
#pragma unroll
        for (int nt = 0; nt < 4; nt++) {
            int n = w * 64 + nt * 16 + l16;
            f32x4 a0 = z4, a1 = z4;
#pragma unroll
            for (int ks = 0; ks < 8; ks++) {
                bf16x8 bv = ld_bf8(&Wq_t[qkbase + (nt * 8 + ks) * 512]);
                a0 = MFMA16(af[0][ks], bv, a0);
                a1 = MFMA16(af[1][ks], bv, a1);
            }
            float bias = bq[n];
#pragma unroll
            for (int r = 0; r < 4; r++) {
                Ab[(quad * 4 + r) * 264 + n]        = (__bf16)(a0[r] + bias);
                Ab[(16 + quad * 4 + r) * 264 + n]   = (__bf16)(a1[r] + bias);
            }
        }
    }
    // no barrier: S3 wave w reads exactly the cols wave w just wrote

    // ---- S3: attention, head = w, 32 rows ------------------------------------
    {
        const int h = w;
        __bf16* Psw = PsB + w * 32 * 72;
        bf16x8 qa[2][2];
#pragma unroll
        for (int rt = 0; rt < 2; rt++)
#pragma unroll
            for (int k0 = 0; k0 < 2; k0++)
                qa[rt][k0] = ld_bf8(&Ab[(rt * 16 + l16) * 264 + h * 64 + k0 * 32 + quad * 8]);
        f32x4 sa[2][4];
#pragma unroll
        for (int rt = 0; rt < 2; rt++)
#pragma unroll
            for (int nt = 0; nt < 4; nt++) sa[rt][nt] = z4;
#pragma unroll
        for (int nt = 0; nt < 4; nt++)
#pragma unroll
            for (int k0 = 0; k0 < 2; k0++) {
                bf16x8 kv8 = ld_bf8(&kb[kvbase + (nt * 2 + k0) * 512]);
                sa[0][nt] = MFMA16(qa[0][k0], kv8, sa[0][nt]);
                sa[1][nt] = MFMA16(qa[1][k0], kv8, sa[1][nt]);
            }
        // softmax per row; P -> Psw (bf16)
#pragma unroll
        for (int rt = 0; rt < 2; rt++)
#pragma unroll
            for (int r = 0; r < 4; r++) {
                float e0 = sa[rt][0][r] * 0.25f, e1 = sa[rt][1][r] * 0.25f;
                float e2 = sa[rt][2][r] * 0.25f, e3 = sa[rt][3][r] * 0.25f;
                float mx = fmaxf(fmaxf(e0, e1), fmaxf(e2, e3));
#pragma unroll
                for (int off = 1; off < 16; off <<= 1) mx = fmaxf(mx, __shfl_xor(mx, off));
                e0 = __expf(e0 - mx); e1 = __expf(e1 - mx);
                e2 = __expf(e2 - mx); e3 = __expf(e3 - mx);
                float sum = e0 + e1 + e2 + e3;
#pragma unroll
                for (int off = 1; off < 16; off <<= 1) sum += __shfl_xor(sum, off);
                float inv = 1.f / sum;
                int row = rt * 16 + quad * 4 + r;
                Psw[row * 72 +  0 + l16] = (__bf16)(e0 * inv);
                Psw[row * 72 + 16 + l16] = (__bf16)(e1 * inv);
                Psw[row * 72 + 32 + l16] = (__bf16)(e2 * inv);
                Psw[row * 72 + 48 + l16] = (__bf16)(e3 * inv);
            }
        // O = P @ V_h -> Ab cols [h*64, h*64+64)
        bf16x8 pa[2][2];
#pragma unroll
        for (int rt = 0; rt < 2; rt++)
#pragma unroll
            for (int k0 = 0; k0 < 2; k0++)
                pa[rt][k0] = ld_bf8(&Psw[(rt * 16 + l16) * 72 + k0 * 32 + quad * 8]);
#pragma unroll
        for (int nt = 0; nt < 4; nt++) {
            f32x4 o0 = z4, o1 = z4;
#pragma unroll
            for (int k0 = 0; k0 < 2; k0++) {
                bf16x8 vv = ld_bf8(&vt[kvbase + (nt * 2 + k0) * 512]);
                o0 = MFMA16(pa[0][k0], vv, o0);
                o1 = MFMA16(pa[1][k0], vv, o1);
            }
#pragma unroll
            for (int r = 0; r < 4; r++) {
                Ab[(quad * 4 + r) * 264 + h * 64 + nt * 16 + l16]      = (__bf16)o0[r];
                Ab[(16 + quad * 4 + r) * 264 + h * 64 + nt * 16 + l16] = (__bf16)o1[r];
            }
        }
    }
    __syncthreads();

    // ---- S4: sc = Ab @ Wo + bo -> f32 registers (no LDS) ---------------------
    f32x4 scf[2][4];
    {
        bf16x8 af[2][8];
#pragma unroll
        for (int rt = 0; rt < 2; rt++)
#pragma unroll
            for (int ks = 0; ks < 8; ks++)
                af[rt][ks] = ld_bf8(&Ab[(rt * 16 + l16) * 264 + ks * 32 + quad * 8]);
#pragma unroll
        for (int nt = 0; nt < 4; nt++) {
            int n = w * 64 + nt * 16 + l16;
            f32x4 a0 = z4, a1 = z4;
#pragma unroll
            for (int ks = 0; ks < 8; ks++) {
                bf16x8 bv = ld_bf8(&Wo_t[qkbase + (nt * 8 + ks) * 512]);
                a0 = MFMA16(af[0][ks], bv, a0);
                a1 = MFMA16(af[1][ks], bv, a1);
            }
            float bias = bo[n];
#pragma unroll
            for (int r = 0; r < 4; r++) { a0[r] += bias; a1[r] += bias; }
            scf[0][nt] = a0;
            scf[1][nt] = a1;
        }
    }

    // ---- S5: row stats of sc from registers ----------------------------------
    {
#pragma unroll
        for (int rt = 0; rt < 2; rt++)
#pragma unroll
            for (int r = 0; r < 4; r++) {
                float s = scf[rt][0][r] + scf[rt][1][r] + scf[rt][2][r] + scf[rt][3][r];
                float q = scf[rt][0][r] * scf[rt][0][r] + scf[rt][1][r] * scf[rt][1][r]
                        + scf[rt][2][r] * scf[rt][2][r] + scf[rt][3][r] * scf[rt][3][r];
#pragma unroll
                for (int mk = 1; mk < 16; mk <<= 1) { s += __shfl_xor(s, mk); q += __shfl_xor(q, mk); }
                if (l16 == 0) {
                    int row = rt * 16 + quad * 4 + r;
                    psum[row * 4 + w] = s;
                    psq[row * 4 + w]  = q;
                }
            }
    }
    __syncthreads();
    if (t < 32) {
        float S = psum[t * 4] + psum[t * 4 + 1] + psum[t * 4 + 2] + psum[t * 4 + 3];
        float Q = psq[t * 4]  + psq[t * 4 + 1]  + psq[t * 4 + 2]  + psq[t * 4 + 3];
        float m = S * (1.f / 256.f);
        float var = Q * (1.f / 256.f) - m * m;
        rowred[t * 2] = m; rowred[t * 2 + 1] = rsqrtf(var + EPSF);
    }
    __syncthreads();

    // ---- LN_f from registers -> Ab; fold scf+bf2 into acc2 (kills scf) -------
    f32x4 acc2[2][4];
    {
        float gf[4], bff[4];
#pragma unroll
        for (int nt = 0; nt < 4; nt++) {
            int n = w * 64 + nt * 16 + l16;
            gf[nt] = lnf_g[n]; bff[nt] = lnf_b[n];
        }
#pragma unroll
        for (int rt = 0; rt < 2; rt++)
#pragma unroll
            for (int r = 0; r < 4; r++) {
                int row = rt * 16 + quad * 4 + r;
                float m = rowred[row * 2], ri = rowred[row * 2 + 1];
#pragma unroll
                for (int nt = 0; nt < 4; nt++) {
                    int n = w * 64 + nt * 16 + l16;
                    Ab[row * 264 + n] = (__bf16)((scf[rt][nt][r] - m) * ri * gf[nt] + bff[nt]);
                }
            }
#pragma unroll
        for (int nt = 0; nt < 4; nt++) {
            float b2 = bf2[w * 64 + nt * 16 + l16];
#pragma unroll
            for (int rt = 0; rt < 2; rt++) {
                acc2[rt][nt] = scf[rt][nt];
#pragma unroll
                for (int r = 0; r < 4; r++) acc2[rt][nt][r] += b2;
            }
        }
    }
    __syncthreads();

    // ---- FFN: FF1 full-width into H (overlay), one exchange barrier, FF2 -----
    {
        bf16x8 fa[2][8];
#pragma unroll
        for (int rt = 0; rt < 2; rt++)
#pragma unroll
            for (int ks = 0; ks < 8; ks++)
                fa[rt][ks] = ld_bf8(&Ab[(rt * 16 + l16) * 264 + ks * 32 + quad * 8]);
        __syncthreads();   // all fa loaded; H overlay (covers Ab+PsB) now safe
        // FF1: wave w computes h1 cols [w*128, w*128+128) for all 32 rows
#pragma unroll
        for (int c = 0; c < 8; c++) {
            int n1 = w * 128 + c * 16 + l16;
            f32x4 h0 = z4, h1 = z4;
#pragma unroll
            for (int ks = 0; ks < 8; ks++) {
                bf16x8 bv = ld_bf8(&Wf1_t[ffbase + (c * 8 + ks) * 512]);
                h0 = MFMA16(fa[0][ks], bv, h0);
                h1 = MFMA16(fa[1][ks], bv, h1);
            }
            float b1v = bf1[n1];
#pragma unroll
            for (int r = 0; r < 4; r++) {
                float u0 = h0[r] + b1v;
                float u1 = h1[r] + b1v;
                H[(quad * 4 + r) * 536 + n1]      = (__bf16)(u0 / (1.f + __expf(-u0)));
                H[(16 + quad * 4 + r) * 536 + n1] = (__bf16)(u1 / (1.f + __expf(-u1)));
            }
        }
        __syncthreads();   // full H visible
        // FF2: accumulate over K=512
#pragma unroll
        for (int k0 = 0; k0 < 16; k0++) {
            bf16x8 ha0 = ld_bf8(&H[(size_t)l16 * 536 + k0 * 32 + quad * 8]);
            bf16x8 ha1 = ld_bf8(&H[(size_t)(16 + l16) * 536 + k0 * 32 + quad * 8]);
#pragma unroll
            for (int nt = 0; nt < 4; nt++) {
                bf16x8 bv = ld_bf8(&Wf2_t[ffbase + (nt * 16 + k0) * 512]);
                acc2[0][nt] = MFMA16(ha0, bv, acc2[0][nt]);
                acc2[1][nt] = MFMA16(ha1, bv, acc2[1][nt]);
            }
        }
    }
    __syncthreads();   // all H reads done before T overlay writes

    // ---- sc_final (= acc2, includes sc + bf2) -> T (f32 transpose) -----------
    {
#pragma unroll
        for (int nt = 0; nt < 4; nt++) {
            int n = w * 64 + nt * 16 + l16;
#pragma unroll
            for (int rt = 0; rt < 2; rt++)
#pragma unroll
                for (int r = 0; r < 4; r++)
                    T[(rt * 16 + quad * 4 + r) * 268 + n] = acc2[rt][nt][r];
        }
    }
    __syncthreads();

    // ---- S6: out[b,c,s] = GN(x)*scale + shift + sc*gamma ---------------------
    {
        const float scl = gp[b * 512 + t];
        const float sft = gp[b * 512 + 256 + t];
        const float gm  = gamma[t];
        const float4* xp = (const float4*)(x + (size_t)(b * 256 + t) * 4096 + s0);
        float4* op = (float4*)(out + (size_t)(b * 256 + t) * 4096 + s0);
#pragma unroll
        for (int ii = 0; ii < 8; ii++) {
            float4 xv = xp[ii];
            float4 o;
            o.x = (xv.x - mg) * rg * scl + sft + T[(ii * 4 + 0) * 268 + t] * gm;
            o.y = (xv.y - mg) * rg * scl + sft + T[(ii * 4 + 1) * 268 + t] * gm;
            o.z = (xv.z - mg) * rg * scl + sft + T[(ii * 4 + 2) * 268 + t] * gm;
            o.w = (xv.w - mg) * rg * scl + sft + T[(ii * 4 + 3) * 268 + t] * gm;
            op[ii] = o;
        }
    }
}

// ============================================================================
extern "C" void kernel_launch(void* const* d_in, const int* in_sizes, int n_in,
                              void* d_out, int out_size, void* d_ws, size_t ws_size,
                              hipStream_t stream) {
    (void)in_sizes; (void)n_in; (void)out_size; (void)ws_size;
    const float* x      = (const float*)d_in[0];
    const float* style  = (const float*)d_in[1];
    const float* Wg     = (const float*)d_in[2];
    const float* bg     = (const float*)d_in[3];
    const float* tokens = (const float*)d_in[4];
    const float* Ws     = (const float*)d_in[5];
    const float* bs     = (const float*)d_in[6];
    const float* Wp1    = (const float*)d_in[7];
    const float* bp1    = (const float*)d_in[8];
    const float* Wp2    = (const float*)d_in[9];
    const float* bp2    = (const float*)d_in[10];
    const float* ln_t_g = (const float*)d_in[11];
    const float* ln_t_b = (const float*)d_in[12];
    const float* ln_q_g = (const float*)d_in[13];
    const float* ln_q_b = (const float*)d_in[14];
    const float* ln_f_g = (const float*)d_in[15];
    const float* ln_f_b = (const float*)d_in[16];
    const float* Wq     = (const float*)d_in[17];
    const float* bq     = (const float*)d_in[18];
    const float* Wk     = (const float*)d_in[19];
    const float* bk     = (const float*)d_in[20];
    const float* Wv     = (const float*)d_in[21];
    const float* bv     = (const float*)d_in[22];
    const float* Wo     = (const float*)d_in[23];
    const float* bo     = (const float*)d_in[24];
    const float* Wf1    = (const float*)d_in[25];
    const float* bf1    = (const float*)d_in[26];
    const float* Wf2    = (const float*)d_in[27];
    const float* bf2    = (const float*)d_in[28];
    const float* gamma  = (const float*)d_in[29];
    float* out = (float*)d_out;

    // d_ws layout (~7.1 MB)
    float* ws = (float*)d_ws;
    float* part  = ws;               // 2048
    float* stats = part  + 2048;     // 128  (unused, kept for layout stability)
    float* gpb   = stats + 128;      // 8192
    float* tmp_s = gpb   + 8192;     // 4096 (unused)
    float* tokb  = tmp_s + 4096;     // 262144 (unused)
    float* posb  = tokb  + 262144;   // 1048576
    unsigned short* kb16  = (unsigned short*)(posb + 1048576); // 262144 bf16
    unsigned short* vt16  = kb16  + 262144;                    // 262144
    unsigned short* wq_t  = vt16  + 262144;                    // 65536
    unsigned short* wo_t  = wq_t  + 65536;                     // 65536
    unsigned short* wf1_t = wo_t  + 65536;                     // 131072
    unsigned short* wf2_t = wf1_t + 131072;                    // 131072

    setup1_kernel<<<1952, 256, 0, stream>>>(x, part, style, Wg, bg, Ws, bs, gpb,
                                            Wp1, bp1, Wp2, bp2, posb,
                                            Wq, Wo, Wf1, Wf2,
                                            wq_t, wo_t, wf1_t, wf2_t,
                                            tokens, ln_t_g, ln_t_b,
                                            Wk, bk, Wv, bv, kb16, vt16);
    mega_kernel<<<2048, 256, 0, stream>>>(x, part, posb,
                                          (const __bf16*)kb16, (const __bf16*)vt16, gpb,
                                          ln_q_g, ln_q_b, ln_f_g, ln_f_b,
                                          (const __bf16*)wq_t, bq,
                                          (const __bf16*)wo_t, bo,
                                          (const __bf16*)wf1_t, bf1,
                                          (const __bf16*)wf2_t, bf2,
                                          gamma, out);
}

// Round 7
// 327.551 us; speedup vs baseline: 1.1334x; 1.1168x over previous
//
#include <hip/hip_runtime.h>
#include <hip/hip_bf16.h>

#define EPSF 1e-5f

typedef __bf16 bf16x8 __attribute__((ext_vector_type(8)));
typedef float  f32x4  __attribute__((ext_vector_type(4)));
#define MFMA16(a, b, c) __builtin_amdgcn_mfma_f32_16x16x32_bf16((a), (b), (c), 0, 0, 0)

__device__ __forceinline__ bf16x8 ld_bf8(const __bf16* p) { return *(const bf16x8*)p; }

__device__ __forceinline__ unsigned short f2bf(float x) {
    unsigned int u = __float_as_uint(x);
    unsigned int r = (u + 0x7fffu + ((u >> 16) & 1u)) >> 16;
    return (unsigned short)r;
}

// Packed fragment layout: [n>>4][k>>5][(k>>3)&3][n&15][k&7]
// -> per (16-col tile, 32-k slice) one wave B-fragment = 1024 contiguous bytes.
__device__ __forceinline__ size_t pk_idx(int n, int k, int K) {
    return ((size_t)(((n >> 4) * (K >> 5) + (k >> 5)) * 4 + ((k >> 3) & 3)) * 16
            + (n & 15)) * 8 + (k & 7);
}

// ============================================================================
// setup1 (unchanged from R6): kvproj | stylegp | pos | 4x wtrans | gn
// grid = 256 + 32 + 256 + 64 + 64 + 128 + 128 + 1024 = 1952
// ============================================================================
__device__ void wtrans_body(const float* __restrict__ W, unsigned short* __restrict__ Wt,
                            int K, int N, int L, int t, float* tile /*32x33*/) {
    int ktiles = K >> 5;
    int kt = L % ktiles, ntl = L / ktiles;
    int k0 = kt * 32, n0 = ntl * 32;
    int tc = t & 31, tr = t >> 5;
#pragma unroll
    for (int j = 0; j < 4; j++)
        tile[(tr + j * 8) * 33 + tc] = W[(size_t)(k0 + tr + j * 8) * N + n0 + tc];
    __syncthreads();
#pragma unroll
    for (int j = 0; j < 4; j++) {
        int r = tr + j * 8;
        Wt[pk_idx(n0 + r, k0 + tc, K)] = f2bf(tile[tc * 33 + r]);
    }
}

__global__ __launch_bounds__(256) void setup1_kernel(
    const float* __restrict__ x, float* __restrict__ part,
    const float* __restrict__ style, const float* __restrict__ Wg,
    const float* __restrict__ bg, const float* __restrict__ Ws,
    const float* __restrict__ bs, float* __restrict__ gp,
    const float* __restrict__ Wp1, const float* __restrict__ bp1,
    const float* __restrict__ Wp2, const float* __restrict__ bp2,
    float* __restrict__ pos,
    const float* __restrict__ Wq, const float* __restrict__ Wo,
    const float* __restrict__ Wf1, const float* __restrict__ Wf2,
    unsigned short* __restrict__ wq_t, unsigned short* __restrict__ wo_t,
    unsigned short* __restrict__ wf1_t, unsigned short* __restrict__ wf2_t,
    const float* __restrict__ tokens,
    const float* __restrict__ ltg, const float* __restrict__ ltb,
    const float* __restrict__ Wk, const float* __restrict__ bk,
    const float* __restrict__ Wv, const float* __restrict__ bv,
    unsigned short* __restrict__ kb16, unsigned short* __restrict__ vt16)
{
    __shared__ float sm[5248];   // 21 KB, carved per role
    const int L = blockIdx.x, t = threadIdx.x;

    if (L < 256) {
        // ---- kvproj: split-k styleproj + token-LN + split-k K/V proj ---------
        int b = L >> 4, tk0 = (L & 15) * 4;
        float* tr   = sm;            // 1024
        float* st   = sm + 1024;     // 512
        float* prA  = sm + 1536;     // 1024
        float* prKV = sm + 1024;     // 4096 (overlays st/prA in phase C)
        float* red  = sm + 5120;     // 32
        st[t] = style[b * 512 + t];
        st[256 + t] = style[b * 512 + 256 + t];
        __syncthreads();
        const int wv_ = t >> 6, ln = t & 63;
        // phase A: ts = style @ Ws (wave-split-k, unroll 4 for load overlap)
        {
            float a0 = 0.f, a1 = 0.f, a2 = 0.f, a3 = 0.f;
#pragma unroll 4
            for (int i = wv_ * 128; i < wv_ * 128 + 128; i++) {
                float sv = st[i];
                const float* wr = &Ws[(size_t)i * 256];
                a0 += sv * wr[ln];       a1 += sv * wr[64 + ln];
                a2 += sv * wr[128 + ln]; a3 += sv * wr[192 + ln];
            }
            prA[wv_ * 256 + ln]       = a0; prA[wv_ * 256 + 64 + ln]  = a1;
            prA[wv_ * 256 + 128 + ln] = a2; prA[wv_ * 256 + 192 + ln] = a3;
        }
        __syncthreads();
        const float ts = prA[t] + prA[256 + t] + prA[512 + t] + prA[768 + t] + bs[t];
        // phase B: token LN
        const float gv = ltg[t], btv = ltb[t];
#pragma unroll
        for (int j = 0; j < 4; j++) {
            float val = tokens[(tk0 + j) * 256 + t] + ts;
            tr[j * 256 + t] = val;
            float s = val, q = val * val;
#pragma unroll
            for (int off = 32; off; off >>= 1) { s += __shfl_down(s, off); q += __shfl_down(q, off); }
            if (ln == 0) { red[j * 8 + wv_ * 2] = s; red[j * 8 + wv_ * 2 + 1] = q; }
        }
        __syncthreads();
#pragma unroll
        for (int j = 0; j < 4; j++) {
            float s = red[j * 8] + red[j * 8 + 2] + red[j * 8 + 4] + red[j * 8 + 6];
            float q = red[j * 8 + 1] + red[j * 8 + 3] + red[j * 8 + 5] + red[j * 8 + 7];
            float m = s * (1.f / 256.f);
            float var = q * (1.f / 256.f) - m * m;
            float r = rsqrtf(var + EPSF);
            tr[j * 256 + t] = (tr[j * 256 + t] - m) * r * gv + btv;
        }
        __syncthreads();
        // phase C: K (waves 0,1) / V (waves 2,3), each pair split-k by 128
        {
            const int isV = wv_ >> 1, kc2 = wv_ & 1;
            const float* Wm = isV ? Wv : Wk;
            float acc[4][4];
#pragma unroll
            for (int cg = 0; cg < 4; cg++)
#pragma unroll
                for (int j = 0; j < 4; j++) acc[cg][j] = 0.f;
#pragma unroll 2
            for (int i = kc2 * 128; i < kc2 * 128 + 128; i++) {
                const float* wr = &Wm[(size_t)i * 256];
                float w0 = wr[ln], w1 = wr[64 + ln], w2 = wr[128 + ln], w3 = wr[192 + ln];
                float t0 = tr[i], t1 = tr[256 + i], t2 = tr[512 + i], t3 = tr[768 + i];
                acc[0][0] += w0 * t0; acc[0][1] += w0 * t1; acc[0][2] += w0 * t2; acc[0][3] += w0 * t3;
                acc[1][0] += w1 * t0; acc[1][1] += w1 * t1; acc[1][2] += w1 * t2; acc[1][3] += w1 * t3;
                acc[2][0] += w2 * t0; acc[2][1] += w2 * t1; acc[2][2] += w2 * t2; acc[2][3] += w2 * t3;
                acc[3][0] += w3 * t0; acc[3][1] += w3 * t1; acc[3][2] += w3 * t2; acc[3][3] += w3 * t3;
            }
#pragma unroll
            for (int cg = 0; cg < 4; cg++)
#pragma unroll
                for (int j = 0; j < 4; j++)
                    prKV[((isV * 2 + kc2) * 4 + j) * 256 + cg * 64 + ln] = acc[cg][j];
        }
        __syncthreads();
        float ak[4], av4[4];
#pragma unroll
        for (int j = 0; j < 4; j++) {
            ak[j]  = prKV[j * 256 + t]        + prKV[(4 + j) * 256 + t];
            av4[j] = prKV[(8 + j) * 256 + t]  + prKV[(12 + j) * 256 + t];
        }
        float bkv = bk[t], bvv = bv[t];
        // K packed: frag(h, nt, k0) lane l16 = token, elems = head channels
        {
            int h = t >> 6, k0c = (t >> 5) & 1, qd = (t >> 3) & 3, e = t & 7;
#pragma unroll
            for (int j = 0; j < 4; j++) {
                int tok = tk0 + j;
                kb16[(size_t)b * 16384
                     + ((((h * 4 + (tok >> 4)) * 2 + k0c) * 4 + qd) * 16 + (tok & 15)) * 8 + e]
                    = f2bf(ak[j] + bkv);
            }
        }
        // V packed: frag(h, nt, k0) lane l16 = ch, elems = tokens
        {
            int h = t >> 6, ntv = (t >> 4) & 3, l16v = t & 15;
            int k0t = tk0 >> 5, qdt = (tk0 >> 3) & 3, et0 = tk0 & 7;
            ushort4 vp;
            vp.x = f2bf(av4[0] + bvv); vp.y = f2bf(av4[1] + bvv);
            vp.z = f2bf(av4[2] + bvv); vp.w = f2bf(av4[3] + bvv);
            *(ushort4*)&vt16[(size_t)b * 16384
                + ((((h * 4 + ntv) * 2 + k0t) * 4 + qdt) * 16 + l16v) * 8 + et0] = vp;
        }
    } else if (L < 288) {
        // ---- style proj gp: wave-split-k (4 waves x 128 k) + LDS reduce ------
        int lb = L - 256, b = lb >> 1, role = lb & 1;
        float* st = sm;            // 512
        float* pr = sm + 512;      // 4 x 256
        st[t] = style[b * 512 + t];
        st[256 + t] = style[b * 512 + 256 + t];
        __syncthreads();
        {
            int kc = t >> 6, ln = t & 63;
            float a0 = 0.f, a1 = 0.f, a2 = 0.f, a3 = 0.f;
#pragma unroll 4
            for (int i = kc * 128; i < kc * 128 + 128; i++) {
                float sv = st[i];
                const float* wr = &Wg[(size_t)i * 512 + role * 256];
                a0 += sv * wr[ln];       a1 += sv * wr[64 + ln];
                a2 += sv * wr[128 + ln]; a3 += sv * wr[192 + ln];
            }
            pr[kc * 256 + ln]       = a0; pr[kc * 256 + 64 + ln]  = a1;
            pr[kc * 256 + 128 + ln] = a2; pr[kc * 256 + 192 + ln] = a3;
        }
        __syncthreads();
        int c = role * 256 + t;
        float acc = pr[t] + pr[256 + t] + pr[512 + t] + pr[768 + t];
        gp[b * 512 + c] = acc + bg[c];
    } else if (L < 544) {
        // ---- pos: 16 positions per block ------------------------------------
        int r = L - 288, s0 = r * 16;
        float* pe = sm;    // 16 x 256
#pragma unroll
        for (int i = 0; i < 16; i++) {
            int sx = s0 + i;
            float gx = -1.f + 2.f * (float)(sx & 63) * (1.f / 63.f);
            float gy = -1.f + 2.f * (float)(sx >> 6) * (1.f / 63.f);
            float h = gx * Wp1[t] + gy * Wp1[256 + t] + bp1[t];
            pe[i * 256 + t] = h / (1.f + __expf(-h));
        }
        __syncthreads();
        float acc[16];
#pragma unroll
        for (int i = 0; i < 16; i++) acc[i] = 0.f;
#pragma unroll 4
        for (int k = 0; k < 256; k++) {
            float wv = Wp2[k * 256 + t];
#pragma unroll
            for (int i = 0; i < 16; i++) acc[i] += pe[i * 256 + k] * wv;
        }
        float bp = bp2[t];
#pragma unroll
        for (int i = 0; i < 16; i++) pos[(size_t)(s0 + i) * 256 + t] = acc[i] + bp;
    } else if (L < 608) {
        wtrans_body(Wq, wq_t, 256, 256, L - 544, t, sm);
    } else if (L < 672) {
        wtrans_body(Wo, wo_t, 256, 256, L - 608, t, sm);
    } else if (L < 800) {
        wtrans_body(Wf1, wf1_t, 256, 512, L - 672, t, sm);
    } else if (L < 928) {
        wtrans_body(Wf2, wf2_t, 512, 256, L - 800, t, sm);
    } else {
        // ---- GroupNorm partial stats: (b,g) = lg>>4, sub = lg&15 ------------
        int lg = L - 928;
        int bg_ = lg >> 4, sub = lg & 15;
        const float4* p = (const float4*)(x + bg_ * 262144 + sub * 16384);
        float s = 0.f, q = 0.f;
#pragma unroll
        for (int i = 0; i < 16; i++) {
            float4 v = p[i * 256 + t];
            s += v.x + v.y + v.z + v.w;
            q += v.x * v.x + v.y * v.y + v.z * v.z + v.w * v.w;
        }
#pragma unroll
        for (int off = 32; off; off >>= 1) { s += __shfl_down(s, off); q += __shfl_down(q, off); }
        int lane = t & 63, w = t >> 6;
        if (lane == 0) { sm[w * 2] = s; sm[w * 2 + 1] = q; }
        __syncthreads();
        if (t == 0) {
            part[lg * 2]     = sm[0] + sm[2] + sm[4] + sm[6];
            part[lg * 2 + 1] = sm[1] + sm[3] + sm[5] + sm[7];
        }
    }
}

// ============================================================================
// Mega kernel v7: register-pressure release. S4 lazy-A (no af preload); FFN in
// two 256-col halves with H-half in dead PsB region (Ab stays live -> no fa
// preload). Back-half live regs ~60 (was 128) -> no spill, deep load batching.
// LDS = 35,328 B -> 4 blocks/CU.
// ============================================================================
__global__ __launch_bounds__(256, 4) void mega_kernel(
    const float* __restrict__ x, const float* __restrict__ part,
    const float* __restrict__ pos,
    const __bf16* __restrict__ kb, const __bf16* __restrict__ vt,
    const float* __restrict__ gp,
    const float* __restrict__ lnq_g, const float* __restrict__ lnq_b,
    const float* __restrict__ lnf_g, const float* __restrict__ lnf_b,
    const __bf16* __restrict__ Wq_t, const float* __restrict__ bq,
    const __bf16* __restrict__ Wo_t, const float* __restrict__ bo,
    const __bf16* __restrict__ Wf1_t, const float* __restrict__ bf1,
    const __bf16* __restrict__ Wf2_t, const float* __restrict__ bf2,
    const float* __restrict__ gamma, float* __restrict__ out)
{
    __shared__ __align__(16) unsigned char smraw[35328];
    __bf16* Ab  = (__bf16*)smraw;                 // 32 x 264 bf16 = 16,896 B
    __bf16* PsB = (__bf16*)(smraw + 16896);       // 18,432 B scratch region
    float*  T   = (float*)smraw;                  // overlay: 32 x 268 f32 = 34,304 B
    float* psum   = (float*)(smraw + 16896);      // stats overlays (PsB region)
    float* psq    = psum + 256;
    float* rowred = psum + 512;

    const int blk  = blockIdx.x;        // 2048 = 16 b * 128 tiles
    const int b    = blk >> 7;
    const int s0   = (blk & 127) * 32;
    const int t    = threadIdx.x;
    const int w    = t >> 6;
    const int lane = t & 63;
    const int quad = lane >> 4;
    const int l16  = lane & 15;

    // int fragment offsets (SGPR base + 32-bit voffset addressing)
    const int woff   = quad * 128 + l16 * 8;
    const int qkbase = w * 16384 + woff;              // Wq_t / Wo_t: +(nt*8+ks)*512
    const int ffbase = w * 32768 + woff;              // Wf2_t: +(nt*16+kk)*512
    const int kvbase = b * 16384 + w * 4096 + woff;   // kb / vt: +(nt*2+k0)*512

    const f32x4 z4 = {0.f, 0.f, 0.f, 0.f};

    // ---- prologue: GN stats from part ----------------------------------------
    if (t < 64) {
        int g = t >> 4, sub = t & 15;
        float s = part[((b * 4 + g) * 16 + sub) * 2];
        float q = part[((b * 4 + g) * 16 + sub) * 2 + 1];
#pragma unroll
        for (int off = 8; off; off >>= 1) { s += __shfl_xor(s, off); q += __shfl_xor(q, off); }
        if (sub == 0) {
            float m   = s * (1.f / 262144.f);
            float var = q * (1.f / 262144.f) - m * m;
            psum[g]     = m;
            psum[4 + g] = rsqrtf(var + EPSF);
        }
    }
    __syncthreads();
    const float mg = psum[t >> 6];
    const float rg = psum[4 + (t >> 6)];

    // ---- S1: Ab = bf16(GN(x)+pos); row stats; LN_q in place ------------------
    {
        const float4* xp = (const float4*)(x + (size_t)(b * 256 + t) * 4096 + s0);
        float xv[32];
#pragma unroll
        for (int i = 0; i < 8; i++) {
            float4 v = xp[i];
            xv[4*i] = v.x; xv[4*i+1] = v.y; xv[4*i+2] = v.z; xv[4*i+3] = v.w;
        }
#pragma unroll
        for (int i = 0; i < 32; i++)
            Ab[i * 264 + t] = (__bf16)((xv[i] - mg) * rg + pos[(size_t)(s0 + i) * 256 + t]);
    }
    __syncthreads();
    {
        int sl = t & 31, cg = t >> 5;
        float s = 0.f, q = 0.f;
#pragma unroll
        for (int j = 0; j < 4; j++) {
            bf16x8 v8 = ld_bf8(&Ab[sl * 264 + cg * 32 + j * 8]);
#pragma unroll
            for (int e = 0; e < 8; e++) { float f = (float)v8[e]; s += f; q += f * f; }
        }
        psum[cg * 32 + sl] = s; psq[cg * 32 + sl] = q;
    }
    __syncthreads();
    if (t < 32) {
        float S = 0.f, Q = 0.f;
        for (int p = 0; p < 8; p++) { S += psum[p * 32 + t]; Q += psq[p * 32 + t]; }
        float m = S * (1.f / 256.f);
        float var = Q * (1.f / 256.f) - m * m;
        rowred[t * 2] = m; rowred[t * 2 + 1] = rsqrtf(var + EPSF);
    }
    __syncthreads();
    {
        float gq = lnq_g[t], bqv = lnq_b[t];
#pragma unroll
        for (int i = 0; i < 32; i++) {
            float v = (float)Ab[i * 264 + t];
            Ab[i * 264 + t] = (__bf16)((v - rowred[i * 2]) * rowred[i * 2 + 1] * gq + bqv);
        }
    }
    __syncthreads();

    // ---- S2: q = Ab @ Wq + bq -> Ab (af preload required: in-place write) ----
    {
        bf16x8 af[2][8];
#pragma unroll
        for (int rt = 0; rt < 2; rt++)
#pragma unroll
            for (int ks = 0; ks < 8; ks++)
                af[rt][ks] = ld_bf8(&Ab[(rt * 16 + l16) * 264 + ks * 32 + quad * 8]);
        __syncthreads();   // all waves' A-frags loaded before Ab overwrite
#pragma unroll
        for (int nt = 0; nt < 4; nt++) {
            int n = w * 64 + nt * 16 + l16;
            f32x4 a0 = z4, a1 = z4;
#pragma unroll
            for (int ks = 0; ks < 8; ks++) {
                bf16x8 bv = ld_bf8(&Wq_t[qkbase + (nt * 8 + ks) * 512]);
                a0 = MFMA16(af[0][ks], bv, a0);
                a1 = MFMA16(af[1][ks], bv, a1);
            }
            float bias = bq[n];
#pragma unroll
            for (int r = 0; r < 4; r++) {
                Ab[(quad * 4 + r) * 264 + n]        = (__bf16)(a0[r] + bias);
                Ab[(16 + quad * 4 + r) * 264 + n]   = (__bf16)(a1[r] + bias);
            }
        }
    }
    // no barrier: S3 wave w reads exactly the cols wave w just wrote

    // ---- S3: attention, head = w, 32 rows ------------------------------------
    {
        const int h = w;
        __bf16* Psw = PsB + w * 32 * 72;
        bf16x8 qa[2][2];
#pragma unroll
        for (int rt = 0; rt < 2; rt++)
#pragma unroll
            for (int k0 = 0; k0 < 2; k0++)
                qa[rt][k0] = ld_bf8(&Ab[(rt * 16 + l16) * 264 + h * 64 + k0 * 32 + quad * 8]);
        f32x4 sa[2][4];
#pragma unroll
        for (int rt = 0; rt < 2; rt++)
#pragma unroll
            for (int nt = 0; nt < 4; nt++) sa[rt][nt] = z4;
#pragma unroll
        for (int nt = 0; nt < 4; nt++)
#pragma unroll
            for (int k0 = 0; k0 < 2; k0++) {
                bf16x8 kv8 = ld_bf8(&kb[kvbase + (nt * 2 + k0) * 512]);
                sa[0][nt] = MFMA16(qa[0][k0], kv8, sa[0][nt]);
                sa[1][nt] = MFMA16(qa[1][k0], kv8, sa[1][nt]);
            }
        // softmax per row; P -> Psw (bf16)
#pragma unroll
        for (int rt = 0; rt < 2; rt++)
#pragma unroll
            for (int r = 0; r < 4; r++) {
                float e0 = sa[rt][0][r] * 0.25f, e1 = sa[rt][1][r] * 0.25f;
                float e2 = sa[rt][2][r] * 0.25f, e3 = sa[rt][3][r] * 0.25f;
                float mx = fmaxf(fmaxf(e0, e1), fmaxf(e2, e3));
#pragma unroll
                for (int off = 1; off < 16; off <<= 1) mx = fmaxf(mx, __shfl_xor(mx, off));
                e0 = __expf(e0 - mx); e1 = __expf(e1 - mx);
                e2 = __expf(e2 - mx); e3 = __expf(e3 - mx);
                float sum = e0 + e1 + e2 + e3;
#pragma unroll
                for (int off = 1; off < 16; off <<= 1) sum += __shfl_xor(sum, off);
                float inv = 1.f / sum;
                int row = rt * 16 + quad * 4 + r;
                Psw[row * 72 +  0 + l16] = (__bf16)(e0 * inv);
                Psw[row * 72 + 16 + l16] = (__bf16)(e1 * inv);
                Psw[row * 72 + 32 + l16] = (__bf16)(e2 * inv);
                Psw[row * 72 + 48 + l16] = (__bf16)(e3 * inv);
            }
        // O = P @ V_h -> Ab cols [h*64, h*64+64)
        bf16x8 pa[2][2];
#pragma unroll
        for (int rt = 0; rt < 2; rt++)
#pragma unroll
            for (int k0 = 0; k0 < 2; k0++)
                pa[rt][k0] = ld_bf8(&Psw[(rt * 16 + l16) * 72 + k0 * 32 + quad * 8]);
#pragma unroll
        for (int nt = 0; nt < 4; nt++) {
            f32x4 o0 = z4, o1 = z4;
#pragma unroll
            for (int k0 = 0; k0 < 2; k0++) {
                bf16x8 vv = ld_bf8(&vt[kvbase + (nt * 2 + k0) * 512]);
                o0 = MFMA16(pa[0][k0], vv, o0);
                o1 = MFMA16(pa[1][k0], vv, o1);
            }
#pragma unroll
            for (int r = 0; r < 4; r++) {
                Ab[(quad * 4 + r) * 264 + h * 64 + nt * 16 + l16]      = (__bf16)o0[r];
                Ab[(16 + quad * 4 + r) * 264 + h * 64 + nt * 16 + l16] = (__bf16)o1[r];
            }
        }
    }
    __syncthreads();

    // ---- S4: sc = Ab @ Wo + bo -> f32 regs (LAZY A: Ab stable this phase) ----
    f32x4 scf[2][4];
    {
#pragma unroll
        for (int nt = 0; nt < 4; nt++) {
            int n = w * 64 + nt * 16 + l16;
            f32x4 a0 = z4, a1 = z4;
#pragma unroll
            for (int ks = 0; ks < 8; ks++) {
                bf16x8 bv = ld_bf8(&Wo_t[qkbase + (nt * 8 + ks) * 512]);
                a0 = MFMA16(ld_bf8(&Ab[l16 * 264 + ks * 32 + quad * 8]), bv, a0);
                a1 = MFMA16(ld_bf8(&Ab[(16 + l16) * 264 + ks * 32 + quad * 8]), bv, a1);
            }
            float bias = bo[n];
#pragma unroll
            for (int r = 0; r < 4; r++) { a0[r] += bias; a1[r] += bias; }
            scf[0][nt] = a0;
            scf[1][nt] = a1;
        }
    }

    // ---- S5: row stats of sc from registers ----------------------------------
    {
#pragma unroll
        for (int rt = 0; rt < 2; rt++)
#pragma unroll
            for (int r = 0; r < 4; r++) {
                float s = scf[rt][0][r] + scf[rt][1][r] + scf[rt][2][r] + scf[rt][3][r];
                float q = scf[rt][0][r] * scf[rt][0][r] + scf[rt][1][r] * scf[rt][1][r]
                        + scf[rt][2][r] * scf[rt][2][r] + scf[rt][3][r] * scf[rt][3][r];
#pragma unroll
                for (int mk = 1; mk < 16; mk <<= 1) { s += __shfl_xor(s, mk); q += __shfl_xor(q, mk); }
                if (l16 == 0) {
                    int row = rt * 16 + quad * 4 + r;
                    psum[row * 4 + w] = s;
                    psq[row * 4 + w]  = q;
                }
            }
    }
    __syncthreads();
    if (t < 32) {
        float S = psum[t * 4] + psum[t * 4 + 1] + psum[t * 4 + 2] + psum[t * 4 + 3];
        float Q = psq[t * 4]  + psq[t * 4 + 1]  + psq[t * 4 + 2]  + psq[t * 4 + 3];
        float m = S * (1.f / 256.f);
        float var = Q * (1.f / 256.f) - m * m;
        rowred[t * 2] = m; rowred[t * 2 + 1] = rsqrtf(var + EPSF);
    }
    __syncthreads();

    // ---- LN_f from registers -> Ab; fold scf+bf2 into acc2 (kills scf) -------
    f32x4 acc2[2][4];
    {
        float gf[4], bff[4];
#pragma unroll
        for (int nt = 0; nt < 4; nt++) {
            int n = w * 64 + nt * 16 + l16;
            gf[nt] = lnf_g[n]; bff[nt] = lnf_b[n];
        }
#pragma unroll
        for (int rt = 0; rt < 2; rt++)
#pragma unroll
            for (int r = 0; r < 4; r++) {
                int row = rt * 16 + quad * 4 + r;
                float m = rowred[row * 2], ri = rowred[row * 2 + 1];
#pragma unroll
                for (int nt = 0; nt < 4; nt++) {
                    int n = w * 64 + nt * 16 + l16;
                    Ab[row * 264 + n] = (__bf16)((scf[rt][nt][r] - m) * ri * gf[nt] + bff[nt]);
                }
            }
#pragma unroll
        for (int nt = 0; nt < 4; nt++) {
            float b2 = bf2[w * 64 + nt * 16 + l16];
#pragma unroll
            for (int rt = 0; rt < 2; rt++) {
                acc2[rt][nt] = scf[rt][nt];
#pragma unroll
                for (int r = 0; r < 4; r++) acc2[rt][nt][r] += b2;
            }
        }
    }
    __syncthreads();   // LN_f(Ab) visible to all waves

    // ---- FFN: two 256-col halves. H-half in PsB (stats dead); Ab stays live --
    {
        __bf16* H1 = PsB;   // 32 x 264 bf16 = 16,896 B (P, psum/psq/rowred dead)
#pragma unroll
        for (int hh = 0; hh < 2; hh++) {
            // FF1 half: wave w computes h1 cols hh*256 + [w*64, +64), lazy A
#pragma unroll
            for (int nt = 0; nt < 4; nt++) {
                const int tile1 = hh * 16 + w * 4 + nt;
                f32x4 h0 = z4, h1v = z4;
#pragma unroll
                for (int ks = 0; ks < 8; ks++) {
                    bf16x8 bv = ld_bf8(&Wf1_t[(tile1 * 8 + ks) * 512 + woff]);
                    h0  = MFMA16(ld_bf8(&Ab[l16 * 264 + ks * 32 + quad * 8]), bv, h0);
                    h1v = MFMA16(ld_bf8(&Ab[(16 + l16) * 264 + ks * 32 + quad * 8]), bv, h1v);
                }
                const int hc = w * 64 + nt * 16 + l16;
                float b1v = bf1[hh * 256 + hc];
#pragma unroll
                for (int r = 0; r < 4; r++) {
                    float u0 = h0[r] + b1v;
                    float u1 = h1v[r] + b1v;
                    H1[(quad * 4 + r) * 264 + hc]      = (__bf16)(u0 / (1.f + __expf(-u0)));
                    H1[(16 + quad * 4 + r) * 264 + hc] = (__bf16)(u1 / (1.f + __expf(-u1)));
                }
            }
            __syncthreads();   // H1 half complete
            // FF2 half: accumulate K-chunk hh*256..+256
#pragma unroll
            for (int k0 = 0; k0 < 8; k0++) {
                bf16x8 ha0 = ld_bf8(&H1[l16 * 264 + k0 * 32 + quad * 8]);
                bf16x8 ha1 = ld_bf8(&H1[(16 + l16) * 264 + k0 * 32 + quad * 8]);
#pragma unroll
                for (int nt = 0; nt < 4; nt++) {
                    bf16x8 bv = ld_bf8(&Wf2_t[ffbase + (nt * 16 + hh * 8 + k0) * 512]);
                    acc2[0][nt] = MFMA16(ha0, bv, acc2[0][nt]);
                    acc2[1][nt] = MFMA16(ha1, bv, acc2[1][nt]);
                }
            }
            __syncthreads();   // FF2 reads done before next H1 write / T overlay
        }
    }

    // ---- sc_final (= acc2, includes sc + bf2) -> T (f32 transpose) -----------
    {
#pragma unroll
        for (int nt = 0; nt < 4; nt++) {
            int n = w * 64 + nt * 16 + l16;
#pragma unroll
            for (int rt = 0; rt < 2; rt++)
#pragma unroll
                for (int r = 0; r < 4; r++)
                    T[(rt * 16 + quad * 4 + r) * 268 + n] = acc2[rt][nt][r];
        }
    }
    __syncthreads();

    // ---- S6: out[b,c,s] = GN(x)*scale + shift + sc*gamma ---------------------
    {
        const float scl = gp[b * 512 + t];
        const float sft = gp[b * 512 + 256 + t];
        const float gm  = gamma[t];
        const float4* xp = (const float4*)(x + (size_t)(b * 256 + t) * 4096 + s0);
        float4* op = (float4*)(out + (size_t)(b * 256 + t) * 4096 + s0);
#pragma unroll
        for (int ii = 0; ii < 8; ii++) {
            float4 xv = xp[ii];
            float4 o;
            o.x = (xv.x - mg) * rg * scl + sft + T[(ii * 4 + 0) * 268 + t] * gm;
            o.y = (xv.y - mg) * rg * scl + sft + T[(ii * 4 + 1) * 268 + t] * gm;
            o.z = (xv.z - mg) * rg * scl + sft + T[(ii * 4 + 2) * 268 + t] * gm;
            o.w = (xv.w - mg) * rg * scl + sft + T[(ii * 4 + 3) * 268 + t] * gm;
            op[ii] = o;
        }
    }
}

// ============================================================================
extern "C" void kernel_launch(void* const* d_in, const int* in_sizes, int n_in,
                              void* d_out, int out_size, void* d_ws, size_t ws_size,
                              hipStream_t stream) {
    (void)in_sizes; (void)n_in; (void)out_size; (void)ws_size;
    const float* x      = (const float*)d_in[0];
    const float* style  = (const float*)d_in[1];
    const float* Wg     = (const float*)d_in[2];
    const float* bg     = (const float*)d_in[3];
    const float* tokens = (const float*)d_in[4];
    const float* Ws     = (const float*)d_in[5];
    const float* bs     = (const float*)d_in[6];
    const float* Wp1    = (const float*)d_in[7];
    const float* bp1    = (const float*)d_in[8];
    const float* Wp2    = (const float*)d_in[9];
    const float* bp2    = (const float*)d_in[10];
    const float* ln_t_g = (const float*)d_in[11];
    const float* ln_t_b = (const float*)d_in[12];
    const float* ln_q_g = (const float*)d_in[13];
    const float* ln_q_b = (const float*)d_in[14];
    const float* ln_f_g = (const float*)d_in[15];
    const float* ln_f_b = (const float*)d_in[16];
    const float* Wq     = (const float*)d_in[17];
    const float* bq     = (const float*)d_in[18];
    const float* Wk     = (const float*)d_in[19];
    const float* bk     = (const float*)d_in[20];
    const float* Wv     = (const float*)d_in[21];
    const float* bv     = (const float*)d_in[22];
    const float* Wo     = (const float*)d_in[23];
    const float* bo     = (const float*)d_in[24];
    const float* Wf1    = (const float*)d_in[25];
    const float* bf1    = (const float*)d_in[26];
    const float* Wf2    = (const float*)d_in[27];
    const float* bf2    = (const float*)d_in[28];
    const float* gamma  = (const float*)d_in[29];
    float* out = (float*)d_out;

    // d_ws layout (~7.1 MB)
    float* ws = (float*)d_ws;
    float* part  = ws;               // 2048
    float* stats = part  + 2048;     // 128  (unused, kept for layout stability)
    float* gpb   = stats + 128;      // 8192
    float* tmp_s = gpb   + 8192;     // 4096 (unused)
    float* tokb  = tmp_s + 4096;     // 262144 (unused)
    float* posb  = tokb  + 262144;   // 1048576
    unsigned short* kb16  = (unsigned short*)(posb + 1048576); // 262144 bf16
    unsigned short* vt16  = kb16  + 262144;                    // 262144
    unsigned short* wq_t  = vt16  + 262144;                    // 65536
    unsigned short* wo_t  = wq_t  + 65536;                     // 65536
    unsigned short* wf1_t = wo_t  + 65536;                     // 131072
    unsigned short* wf2_t = wf1_t + 131072;                    // 131072

    setup1_kernel<<<1952, 256, 0, stream>>>(x, part, style, Wg, bg, Ws, bs, gpb,
                                            Wp1, bp1, Wp2, bp2, posb,
                                            Wq, Wo, Wf1, Wf2,
                                            wq_t, wo_t, wf1_t, wf2_t,
                                            tokens, ln_t_g, ln_t_b,
                                            Wk, bk, Wv, bv, kb16, vt16);
    mega_kernel<<<2048, 256, 0, stream>>>(x, part, posb,
                                          (const __bf16*)kb16, (const __bf16*)vt16, gpb,
                                          ln_q_g, ln_q_b, ln_f_g, ln_f_b,
                                          (const __bf16*)wq_t, bq,
                                          (const __bf16*)wo_t, bo,
                                          (const __bf16*)wf1_t, bf1,
                                          (const __bf16*)wf2_t, bf2,
                                          gamma, out);
}